// Round 4
// baseline (572.107 us; speedup 1.0000x reference)
//
#include <hip/hip_runtime.h>
#include <math.h>

#define NB 8
#define NT 32
#define NAG 50
#define MTASK 100
#define MTOP 10
#define NNB 10
#define LDIM 5
#define HDIM 512
#define INDIM 1610
#define KP1 1632            // INDIM padded to multiple of 32
#define NROWS (NB*NT*NAG)   // 12800
#define NOUT (MTOP+1)       // 11

typedef float f32x4 __attribute__((ext_vector_type(4)));
typedef __bf16 bf16x8 __attribute__((ext_vector_type(8)));

__device__ __forceinline__ void gload16(const __bf16* g, __bf16* l) {
    __builtin_amdgcn_global_load_lds(
        (__attribute__((address_space(1))) void*)(g),
        (__attribute__((address_space(3))) void*)(l), 16, 0, 0);
}

// ---------------- Fused front-end: one block per (b,t) ----------------
// tb -> top-10 tasks -> best -> neighbors -> 1610-dim features (split bf16)
__global__ __launch_bounds__(256) void k_front(
    const float* __restrict__ beta, const float* __restrict__ actions,
    const float* __restrict__ power, const int* __restrict__ prev,
    __bf16* __restrict__ Ah, __bf16* __restrict__ Al) {
    int bt = blockIdx.x;
    int tid = threadIdx.x, wid = tid >> 6, lane = tid & 63;
    __shared__ float tb[NAG][MTASK];     // 20 KB
    __shared__ float best[NAG][NAG];     // 10 KB
    __shared__ int   tks[NAG][MTOP];
    __shared__ int   nbs[NAG][NNB];
    __shared__ int   pav[NAG];
    __shared__ float pwv[NAG];
    const float* bslice = beta + (size_t)bt * NAG * MTASK * LDIM;

    // phase 1: total_beta
    for (int t = tid; t < NAG * MTASK; t += 256) {
        const float* p = bslice + (size_t)t * LDIM;
        tb[t / MTASK][t % MTASK] = p[0] + p[1] + p[2] + p[3] + p[4];
    }
    if (tid < NAG) { pav[tid] = prev[bt * NAG + tid]; pwv[tid] = power[bt * NAG + tid]; }
    __syncthreads();

    // phase 2: stable top-10 tasks per agent (wave-parallel argmax)
    for (int a = wid; a < NAG; a += 4) {
        float v1 = (lane < MTASK) ? tb[a][lane] : -INFINITY;
        float v2 = (lane + 64 < MTASK) ? tb[a][lane + 64] : -INFINITY;
        for (int k = 0; k < MTOP; ++k) {
            float v; int idx;
            if (v1 >= v2) { v = v1; idx = lane; } else { v = v2; idx = lane + 64; }
            #pragma unroll
            for (int m = 1; m < 64; m <<= 1) {
                float vo = __shfl_xor(v, m, 64);
                int io = __shfl_xor(idx, m, 64);
                if (vo > v || (vo == v && io < idx)) { v = vo; idx = io; }
            }
            if (lane == 0) tks[a][k] = idx;
            if (idx == lane) v1 = -INFINITY;
            else if (idx == lane + 64) v2 = -INFINITY;
        }
    }
    __syncthreads();

    // phase 3: best[i][a] = max_k tb[a][tasks[i][k]], diag -inf
    for (int t = tid; t < NAG * NAG; t += 256) {
        int i = t / NAG, a = t - i * NAG;
        float mx = -INFINITY;
        #pragma unroll
        for (int k = 0; k < MTOP; ++k) mx = fmaxf(mx, tb[a][tks[i][k]]);
        best[i][a] = (a == i) ? -INFINITY : mx;
    }
    __syncthreads();

    // phase 4: stable top-10 neighbors per agent
    for (int i = wid; i < NAG; i += 4) {
        float v1 = (lane < NAG) ? best[i][lane] : -INFINITY;
        for (int k = 0; k < NNB; ++k) {
            float v = v1; int idx = lane;
            #pragma unroll
            for (int m = 1; m < 64; m <<= 1) {
                float vo = __shfl_xor(v, m, 64);
                int io = __shfl_xor(idx, m, 64);
                if (vo > v || (vo == v && io < idx)) { v = vo; idx = io; }
            }
            if (lane == 0) nbs[i][k] = idx;
            if (idx == lane) v1 = -INFINITY;
        }
    }
    __syncthreads();

    // phase 5: build features, split bf16, coalesced along c
    for (int t = tid; t < NAG * KP1; t += 256) {
        int i = t / KP1, c = t - i * KP1;
        float f = 0.f;
        if (c < 500) {
            int k = c / 50, r = c - k * 50, j = r / 5, l = r - j * 5;
            f = bslice[((size_t)nbs[i][j] * MTASK + tks[i][k]) * LDIM + l];
        } else if (c < 1500) {
            int r = c - 500, j = r / MTASK, m = r - j * MTASK;
            f = actions[((size_t)bt * NAG + nbs[i][j]) * MTASK + m];
        } else if (c < 1510) {
            f = pwv[nbs[i][c - 1500]];
        } else if (c < 1610) {
            int r = c - 1510, k = r / NNB, j = r - k * NNB;
            f = (tks[i][k] == pav[nbs[i][j]]) ? 1.f : 0.f;
        }
        size_t off = ((size_t)bt * NAG + i) * KP1 + c;
        __bf16 h = (__bf16)f;
        Ah[off] = h;
        Al[off] = (__bf16)(f - (float)h);
    }
}

// ---------------- Weight prep: W[K][N] -> Wt hi/lo [N][KP] ----------------
__global__ void k_prep_w(const float* __restrict__ W,
                         __bf16* __restrict__ Th, __bf16* __restrict__ Tl,
                         int K, int N, int KP) {
    int idx = blockIdx.x * blockDim.x + threadIdx.x;
    if (idx >= N * KP) return;
    int n = idx / KP, kp = idx - n * KP;
    float f = (kp < K) ? W[(size_t)kp * N + n] : 0.f;
    __bf16 h = (__bf16)f;
    __bf16 l = (__bf16)(f - (float)h);
    Th[idx] = h;
    Tl[idx] = l;
}

// ---------------- 3-pass chunk-interleaved split-bf16 GEMM ----------------
// Tile 64x128, 2 waves. Per K-step stage {Ah,Al,Bh,Bl} chunks once;
// fire AhBh + AlBh + AhBl (48 MFMA / 16 ds_read = 3:1).
template<int KP, bool SPLIT_OUT>
__global__ __launch_bounds__(128, 2) void k_gemm_tri(
    const __bf16* __restrict__ Ahp, const __bf16* __restrict__ Alp,
    const __bf16* __restrict__ Bhp, const __bf16* __restrict__ Blp,
    const float* __restrict__ bias,
    __bf16* __restrict__ Ch, __bf16* __restrict__ Cl, float* __restrict__ Cf) {
    constexpr int NK = KP / 32;
    __shared__ __align__(16) __bf16 sA[2][2][2048];   // [buf][hi/lo][kc(4)*64*8]
    __shared__ __align__(16) __bf16 sB[2][2][4096];   // [buf][hi/lo][kc(4)*128*8]
    int tid = threadIdx.x, wid = tid >> 6, lane = tid & 63;
    int n0 = blockIdx.x * 128, m0 = blockIdx.y * 64;

    auto stage = [&](int kt, int buf) {
        #pragma unroll
        for (int q = 0; q < 2; ++q) {
            int e0 = q * 128 + wid * 64;
            int kc = e0 >> 6;
            const __bf16* gh = Ahp + (size_t)(m0 + lane) * KP + kt * 32 + kc * 8;
            const __bf16* gl = Alp + (size_t)(m0 + lane) * KP + kt * 32 + kc * 8;
            gload16(gh, &sA[buf][0][e0 * 8]);
            gload16(gl, &sA[buf][1][e0 * 8]);
        }
        #pragma unroll
        for (int q = 0; q < 4; ++q) {
            int e0 = q * 128 + wid * 64;
            int kc = e0 >> 7, rb = e0 & 127;
            const __bf16* gh = Bhp + (size_t)(n0 + rb + lane) * KP + kt * 32 + kc * 8;
            const __bf16* gl = Blp + (size_t)(n0 + rb + lane) * KP + kt * 32 + kc * 8;
            gload16(gh, &sB[buf][0][e0 * 8]);
            gload16(gl, &sB[buf][1][e0 * 8]);
        }
    };

    int lrow = lane & 15, lk = lane >> 4;
    int abase = (lk * 64 + lrow) * 8;
    int bbase = (lk * 128 + wid * 64 + lrow) * 8;
    f32x4 acc[4][4] = {};

    stage(0, 0);
    for (int kt = 0; kt < NK; ++kt) {
        int buf = kt & 1;
        __syncthreads();
        if (kt + 1 < NK) stage(kt + 1, buf ^ 1);
        bf16x8 ah[4], al[4], bh[4], bl[4];
        #pragma unroll
        for (int i = 0; i < 4; ++i) {
            ah[i] = *(const bf16x8*)&sA[buf][0][abase + i * 128];
            al[i] = *(const bf16x8*)&sA[buf][1][abase + i * 128];
        }
        #pragma unroll
        for (int j = 0; j < 4; ++j) {
            bh[j] = *(const bf16x8*)&sB[buf][0][bbase + j * 128];
            bl[j] = *(const bf16x8*)&sB[buf][1][bbase + j * 128];
        }
        #pragma unroll
        for (int i = 0; i < 4; ++i)
            #pragma unroll
            for (int j = 0; j < 4; ++j) {
                acc[i][j] = __builtin_amdgcn_mfma_f32_16x16x32_bf16(ah[i], bh[j], acc[i][j], 0, 0, 0);
                acc[i][j] = __builtin_amdgcn_mfma_f32_16x16x32_bf16(al[i], bh[j], acc[i][j], 0, 0, 0);
                acc[i][j] = __builtin_amdgcn_mfma_f32_16x16x32_bf16(ah[i], bl[j], acc[i][j], 0, 0, 0);
            }
    }

    // epilogue: row = i*16 + lk*4 + r, col = n0 + wid*64 + j*16 + lrow
    #pragma unroll
    for (int i = 0; i < 4; ++i) {
        int mrow = m0 + i * 16 + lk * 4;
        #pragma unroll
        for (int j = 0; j < 4; ++j) {
            int n = n0 + wid * 64 + j * 16 + lrow;
            if constexpr (SPLIT_OUT) {
                float bv = bias[n];
                #pragma unroll
                for (int r = 0; r < 4; ++r) {
                    float c = fmaxf(acc[i][j][r] + bv, 0.f);
                    size_t off = (size_t)(mrow + r) * HDIM + n;
                    __bf16 h = (__bf16)c;
                    Ch[off] = h;
                    Cl[off] = (__bf16)(c - (float)h);
                }
            } else {
                #pragma unroll
                for (int r = 0; r < 4; ++r)
                    Cf[(size_t)(mrow + r) * HDIM + n] = acc[i][j][r];
            }
        }
    }
}

// ---------------- output: +b2, relu, @W3 + b3 ; wave per row ----------------
__global__ __launch_bounds__(256) void k_out(const float* __restrict__ h2,
                                             const float* __restrict__ b2,
                                             const float* __restrict__ W3,
                                             const float* __restrict__ b3,
                                             float* __restrict__ out) {
    int wid = threadIdx.x >> 6, lane = threadIdx.x & 63;
    int row = blockIdx.x * 4 + wid;
    const float* hp = h2 + (size_t)row * HDIM + lane * 8;
    f32x4 a0 = *(const f32x4*)hp;
    f32x4 a1 = *(const f32x4*)(hp + 4);
    f32x4 c0 = *(const f32x4*)&b2[lane * 8];
    f32x4 c1 = *(const f32x4*)&b2[lane * 8 + 4];
    float h[8];
    #pragma unroll
    for (int i = 0; i < 4; ++i) {
        h[i] = fmaxf(a0[i] + c0[i], 0.f);
        h[4 + i] = fmaxf(a1[i] + c1[i], 0.f);
    }
    float acc[NOUT];
    #pragma unroll
    for (int n = 0; n < NOUT; ++n) acc[n] = 0.f;
    int k0 = lane * 8;
    #pragma unroll
    for (int i = 0; i < 8; ++i) {
        float hv = h[i];
        const float* w = W3 + (size_t)(k0 + i) * NOUT;
        #pragma unroll
        for (int n = 0; n < NOUT; ++n) acc[n] += hv * w[n];
    }
    #pragma unroll
    for (int off = 32; off >= 1; off >>= 1)
        #pragma unroll
        for (int n = 0; n < NOUT; ++n) acc[n] += __shfl_down(acc[n], off, 64);
    if (lane == 0) {
        #pragma unroll
        for (int n = 0; n < NOUT; ++n) out[(size_t)row * NOUT + n] = acc[n] + b3[n];
    }
}

extern "C" void kernel_launch(void* const* d_in, const int* in_sizes, int n_in,
                              void* d_out, int out_size, void* d_ws, size_t ws_size,
                              hipStream_t stream) {
    const float* beta    = (const float*)d_in[0];
    const float* actions = (const float*)d_in[1];
    const float* power   = (const float*)d_in[2];
    const int*   prev    = (const int*)d_in[3];
    const float* W1      = (const float*)d_in[4];
    const float* b1      = (const float*)d_in[5];
    const float* W2      = (const float*)d_in[6];
    const float* b2      = (const float*)d_in[7];
    const float* W3      = (const float*)d_in[8];
    const float* b3      = (const float*)d_in[9];
    float* out = (float*)d_out;

    char* ws = (char*)d_ws;
    size_t off = 0;
    auto alloc = [&](size_t bytes) { void* p = ws + off; off += (bytes + 255) & ~(size_t)255; return p; };
    __bf16* Ah   = (__bf16*)alloc((size_t)NROWS * KP1 * 2);
    __bf16* Al   = (__bf16*)alloc((size_t)NROWS * KP1 * 2);
    __bf16* W1th = (__bf16*)alloc((size_t)HDIM * KP1 * 2);
    __bf16* W1tl = (__bf16*)alloc((size_t)HDIM * KP1 * 2);
    __bf16* W2th = (__bf16*)alloc((size_t)HDIM * HDIM * 2);
    __bf16* W2tl = (__bf16*)alloc((size_t)HDIM * HDIM * 2);
    __bf16* h1h  = (__bf16*)alloc((size_t)NROWS * HDIM * 2);
    __bf16* h1l  = (__bf16*)alloc((size_t)NROWS * HDIM * 2);
    float*  h2   = (float*) alloc((size_t)NROWS * HDIM * 4);

    k_front<<<NB * NT, 256, 0, stream>>>(beta, actions, power, prev, Ah, Al);
    {
        int n1 = HDIM * KP1;
        k_prep_w<<<(n1 + 255) / 256, 256, 0, stream>>>(W1, W1th, W1tl, INDIM, HDIM, KP1);
        int n2 = HDIM * HDIM;
        k_prep_w<<<(n2 + 255) / 256, 256, 0, stream>>>(W2, W2th, W2tl, HDIM, HDIM, HDIM);
    }
    dim3 g1(HDIM / 128, NROWS / 64);   // n-major: 4 consecutive blocks share one A panel
    k_gemm_tri<KP1, true><<<g1, 128, 0, stream>>>(Ah, Al, W1th, W1tl, b1, h1h, h1l, nullptr);
    dim3 g2(HDIM / 128, NROWS / 64);
    k_gemm_tri<HDIM, false><<<g2, 128, 0, stream>>>(h1h, h1l, W2th, W2tl, nullptr,
                                                    nullptr, nullptr, h2);
    k_out<<<NROWS / 4, 256, 0, stream>>>(h2, b2, W3, b3, out);
}

// Round 5
// 373.382 us; speedup vs baseline: 1.5322x; 1.5322x over previous
//
#include <hip/hip_runtime.h>
#include <math.h>

#define NB 8
#define NT 32
#define NAG 50
#define MTASK 100
#define MTOP 10
#define NNB 10
#define LDIM 5
#define HDIM 512
#define INDIM 1610
#define KP1 1632            // INDIM padded to multiple of 32
#define NROWS (NB*NT*NAG)   // 12800
#define NOUT (MTOP+1)       // 11

typedef float f32x4 __attribute__((ext_vector_type(4)));
typedef __bf16 bf16x8 __attribute__((ext_vector_type(8)));

__device__ __forceinline__ void gload16(const __bf16* g, __bf16* l) {
    __builtin_amdgcn_global_load_lds(
        (__attribute__((address_space(1))) void*)(g),
        (__attribute__((address_space(3))) void*)(l), 16, 0, 0);
}

// ---------------- top-10 tasks, wave per row ----------------
__global__ __launch_bounds__(256) void k_topk(const float* __restrict__ beta,
                                              float* __restrict__ total_beta,
                                              int* __restrict__ tasks) {
    int wid = threadIdx.x >> 6, lane = threadIdx.x & 63;
    int row = blockIdx.x * 4 + wid;              // < 12800
    const float* bp = beta + (size_t)row * MTASK * LDIM;
    float v1 = -INFINITY, v2 = -INFINITY;
    {
        const float* p = bp + lane * LDIM;
        v1 = p[0] + p[1] + p[2] + p[3] + p[4];   // lane < 64 < MTASK always valid
        total_beta[(size_t)row * MTASK + lane] = v1;
    }
    if (lane + 64 < MTASK) {
        const float* p = bp + (lane + 64) * LDIM;
        v2 = p[0] + p[1] + p[2] + p[3] + p[4];
        total_beta[(size_t)row * MTASK + lane + 64] = v2;
    }
    for (int k = 0; k < MTOP; ++k) {
        float v; int idx;
        if (v1 >= v2) { v = v1; idx = lane; } else { v = v2; idx = lane + 64; }
        #pragma unroll
        for (int m = 1; m < 64; m <<= 1) {
            float vo = __shfl_xor(v, m, 64);
            int io = __shfl_xor(idx, m, 64);
            if (vo > v || (vo == v && io < idx)) { v = vo; idx = io; }
        }
        if (lane == 0) tasks[row * MTOP + k] = idx;
        if (idx == lane) v1 = -INFINITY;
        else if (idx == lane + 64) v2 = -INFINITY;
    }
}

// ---------------- neighbors, wave per row ----------------
__global__ __launch_bounds__(256) void k_nbrs(const float* __restrict__ total_beta,
                                              const int* __restrict__ tasks,
                                              int* __restrict__ neighbors) {
    int wid = threadIdx.x >> 6, lane = threadIdx.x & 63;
    int row = blockIdx.x * 4 + wid;
    int bt = row / NAG, i = row - bt * NAG;
    int tk[MTOP];
    #pragma unroll
    for (int k = 0; k < MTOP; ++k) tk[k] = tasks[row * MTOP + k];   // uniform -> broadcast
    float v1 = -INFINITY;
    if (lane < NAG) {
        const float* tba = total_beta + ((size_t)bt * NAG + lane) * MTASK;
        float mx = -INFINITY;
        #pragma unroll
        for (int k = 0; k < MTOP; ++k) mx = fmaxf(mx, tba[tk[k]]);
        v1 = (lane == i) ? -INFINITY : mx;
    }
    for (int k = 0; k < NNB; ++k) {
        float v = v1; int idx = lane;
        #pragma unroll
        for (int m = 1; m < 64; m <<= 1) {
            float vo = __shfl_xor(v, m, 64);
            int io = __shfl_xor(idx, m, 64);
            if (vo > v || (vo == v && io < idx)) { v = vo; idx = io; }
        }
        if (lane == 0) neighbors[row * NNB + k] = idx;
        if (idx == lane) v1 = -INFINITY;
    }
}

// ---------------- build 1610-dim inputs as split bf16, block per row ----------------
__global__ void k_build_inputs(const float* __restrict__ beta,
                               const float* __restrict__ actions,
                               const float* __restrict__ power,
                               const int* __restrict__ prev,
                               const int* __restrict__ tasks,
                               const int* __restrict__ neighbors,
                               __bf16* __restrict__ Ah, __bf16* __restrict__ Al) {
    int row = blockIdx.x;
    int bt = row / NAG;
    __shared__ int tk[MTOP], nb[NNB], pa[NNB];
    __shared__ float pw[NNB];
    if (threadIdx.x < MTOP) tk[threadIdx.x] = tasks[row * MTOP + threadIdx.x];
    if (threadIdx.x >= 32 && threadIdx.x < 32 + NNB) {
        int j = threadIdx.x - 32;
        int nbj = neighbors[row * NNB + j];
        nb[j] = nbj;
        pa[j] = prev[bt * NAG + nbj];
        pw[j] = power[bt * NAG + nbj];
    }
    __syncthreads();
    __bf16* oh = Ah + (size_t)row * KP1;
    __bf16* ol = Al + (size_t)row * KP1;
    for (int idx = threadIdx.x; idx < KP1; idx += blockDim.x) {
        float f = 0.f;
        if (idx < 500) {
            int k = idx / (NNB * LDIM);
            int r = idx - k * (NNB * LDIM);
            int j = r / LDIM;
            int l = r - j * LDIM;
            f = beta[(((size_t)bt * NAG + nb[j]) * MTASK + tk[k]) * LDIM + l];
        } else if (idx < 1500) {
            int i2 = idx - 500;
            int j = i2 / MTASK;
            int m = i2 - j * MTASK;
            f = actions[((size_t)bt * NAG + nb[j]) * MTASK + m];
        } else if (idx < 1510) {
            f = pw[idx - 1500];
        } else if (idx < 1610) {
            int i2 = idx - 1510;
            int k = i2 / NNB;
            int j = i2 - k * NNB;
            f = (tk[k] == pa[j]) ? 1.0f : 0.0f;
        }
        __bf16 h = (__bf16)f;
        __bf16 lo = (__bf16)(f - (float)h);
        oh[idx] = h;
        ol[idx] = lo;
    }
}

// ---------------- Weight prep: W[K][N] -> Wt hi/lo [N][KP] ----------------
__global__ void k_prep_w(const float* __restrict__ W,
                         __bf16* __restrict__ Th, __bf16* __restrict__ Tl,
                         int K, int N, int KP) {
    int idx = blockIdx.x * blockDim.x + threadIdx.x;
    if (idx >= N * KP) return;
    int n = idx / KP, kp = idx - n * KP;
    float f = (kp < K) ? W[(size_t)kp * N + n] : 0.f;
    __bf16 h = (__bf16)f;
    __bf16 l = (__bf16)(f - (float)h);
    Th[idx] = h;
    Tl[idx] = l;
}

// ---------------- 3-pass chunk-interleaved split-bf16 GEMM ----------------
// Tile 64x128, 2 waves, XCD-swizzled 1D grid (800 = 8 XCD x 100).
// Within an XCD chunk, n-tile varies fastest -> 4 consecutive blocks share one
// A panel in that XCD's L2.
template<int KP, bool SPLIT_OUT>
__global__ __launch_bounds__(128, 2) void k_gemm_tri(
    const __bf16* __restrict__ Ahp, const __bf16* __restrict__ Alp,
    const __bf16* __restrict__ Bhp, const __bf16* __restrict__ Blp,
    const float* __restrict__ bias,
    __bf16* __restrict__ Ch, __bf16* __restrict__ Cl, float* __restrict__ Cf) {
    constexpr int NK = KP / 32;
    __shared__ __align__(16) __bf16 sA[2][2][2048];   // [buf][hi/lo][kc(4)*64*8]
    __shared__ __align__(16) __bf16 sB[2][2][4096];   // [buf][hi/lo][kc(4)*128*8]
    int tid = threadIdx.x, wid = tid >> 6, lane = tid & 63;
    int id = blockIdx.x;                       // 0..799
    int swz = (id & 7) * 100 + (id >> 3);      // bijective: 800 % 8 == 0
    int n0 = (swz & 3) * 128, m0 = (swz >> 2) * 64;

    auto stage = [&](int kt, int buf) {
        #pragma unroll
        for (int q = 0; q < 2; ++q) {
            int e0 = q * 128 + wid * 64;
            int kc = e0 >> 6;
            const __bf16* gh = Ahp + (size_t)(m0 + lane) * KP + kt * 32 + kc * 8;
            const __bf16* gl = Alp + (size_t)(m0 + lane) * KP + kt * 32 + kc * 8;
            gload16(gh, &sA[buf][0][e0 * 8]);
            gload16(gl, &sA[buf][1][e0 * 8]);
        }
        #pragma unroll
        for (int q = 0; q < 4; ++q) {
            int e0 = q * 128 + wid * 64;
            int kc = e0 >> 7, rb = e0 & 127;
            const __bf16* gh = Bhp + (size_t)(n0 + rb + lane) * KP + kt * 32 + kc * 8;
            const __bf16* gl = Blp + (size_t)(n0 + rb + lane) * KP + kt * 32 + kc * 8;
            gload16(gh, &sB[buf][0][e0 * 8]);
            gload16(gl, &sB[buf][1][e0 * 8]);
        }
    };

    int lrow = lane & 15, lk = lane >> 4;
    int abase = (lk * 64 + lrow) * 8;
    int bbase = (lk * 128 + wid * 64 + lrow) * 8;
    f32x4 acc[4][4] = {};

    stage(0, 0);
    for (int kt = 0; kt < NK; ++kt) {
        int buf = kt & 1;
        __syncthreads();
        if (kt + 1 < NK) stage(kt + 1, buf ^ 1);
        bf16x8 ah[4], al[4], bh[4], bl[4];
        #pragma unroll
        for (int i = 0; i < 4; ++i) {
            ah[i] = *(const bf16x8*)&sA[buf][0][abase + i * 128];
            al[i] = *(const bf16x8*)&sA[buf][1][abase + i * 128];
        }
        #pragma unroll
        for (int j = 0; j < 4; ++j) {
            bh[j] = *(const bf16x8*)&sB[buf][0][bbase + j * 128];
            bl[j] = *(const bf16x8*)&sB[buf][1][bbase + j * 128];
        }
        #pragma unroll
        for (int i = 0; i < 4; ++i)
            #pragma unroll
            for (int j = 0; j < 4; ++j) {
                acc[i][j] = __builtin_amdgcn_mfma_f32_16x16x32_bf16(ah[i], bh[j], acc[i][j], 0, 0, 0);
                acc[i][j] = __builtin_amdgcn_mfma_f32_16x16x32_bf16(al[i], bh[j], acc[i][j], 0, 0, 0);
                acc[i][j] = __builtin_amdgcn_mfma_f32_16x16x32_bf16(ah[i], bl[j], acc[i][j], 0, 0, 0);
            }
    }

    // epilogue: row = m0 + i*16 + lk*4 + r, col = n0 + wid*64 + j*16 + lrow
    #pragma unroll
    for (int i = 0; i < 4; ++i) {
        int mrow = m0 + i * 16 + lk * 4;
        #pragma unroll
        for (int j = 0; j < 4; ++j) {
            int n = n0 + wid * 64 + j * 16 + lrow;
            if constexpr (SPLIT_OUT) {
                float bv = bias[n];
                #pragma unroll
                for (int r = 0; r < 4; ++r) {
                    float c = fmaxf(acc[i][j][r] + bv, 0.f);
                    size_t off = (size_t)(mrow + r) * HDIM + n;
                    __bf16 h = (__bf16)c;
                    Ch[off] = h;
                    Cl[off] = (__bf16)(c - (float)h);
                }
            } else {
                #pragma unroll
                for (int r = 0; r < 4; ++r)
                    Cf[(size_t)(mrow + r) * HDIM + n] = acc[i][j][r];
            }
        }
    }
}

// ---------------- output: +b2, relu, @W3 + b3 ; wave per row ----------------
__global__ __launch_bounds__(256) void k_out(const float* __restrict__ h2,
                                             const float* __restrict__ b2,
                                             const float* __restrict__ W3,
                                             const float* __restrict__ b3,
                                             float* __restrict__ out) {
    int wid = threadIdx.x >> 6, lane = threadIdx.x & 63;
    int row = blockIdx.x * 4 + wid;
    const float* hp = h2 + (size_t)row * HDIM + lane * 8;
    f32x4 a0 = *(const f32x4*)hp;
    f32x4 a1 = *(const f32x4*)(hp + 4);
    f32x4 c0 = *(const f32x4*)&b2[lane * 8];
    f32x4 c1 = *(const f32x4*)&b2[lane * 8 + 4];
    float h[8];
    #pragma unroll
    for (int i = 0; i < 4; ++i) {
        h[i] = fmaxf(a0[i] + c0[i], 0.f);
        h[4 + i] = fmaxf(a1[i] + c1[i], 0.f);
    }
    float acc[NOUT];
    #pragma unroll
    for (int n = 0; n < NOUT; ++n) acc[n] = 0.f;
    int k0 = lane * 8;
    #pragma unroll
    for (int i = 0; i < 8; ++i) {
        float hv = h[i];
        const float* w = W3 + (size_t)(k0 + i) * NOUT;
        #pragma unroll
        for (int n = 0; n < NOUT; ++n) acc[n] += hv * w[n];
    }
    #pragma unroll
    for (int off = 32; off >= 1; off >>= 1)
        #pragma unroll
        for (int n = 0; n < NOUT; ++n) acc[n] += __shfl_down(acc[n], off, 64);
    if (lane == 0) {
        #pragma unroll
        for (int n = 0; n < NOUT; ++n) out[(size_t)row * NOUT + n] = acc[n] + b3[n];
    }
}

extern "C" void kernel_launch(void* const* d_in, const int* in_sizes, int n_in,
                              void* d_out, int out_size, void* d_ws, size_t ws_size,
                              hipStream_t stream) {
    const float* beta    = (const float*)d_in[0];
    const float* actions = (const float*)d_in[1];
    const float* power   = (const float*)d_in[2];
    const int*   prev    = (const int*)d_in[3];
    const float* W1      = (const float*)d_in[4];
    const float* b1      = (const float*)d_in[5];
    const float* W2      = (const float*)d_in[6];
    const float* b2      = (const float*)d_in[7];
    const float* W3      = (const float*)d_in[8];
    const float* b3      = (const float*)d_in[9];
    float* out = (float*)d_out;

    char* ws = (char*)d_ws;
    size_t off = 0;
    auto alloc = [&](size_t bytes) { void* p = ws + off; off += (bytes + 255) & ~(size_t)255; return p; };
    float*  total_beta = (float*) alloc((size_t)NROWS * MTASK * 4);
    int*    tasks      = (int*)   alloc((size_t)NROWS * MTOP * 4);
    int*    neighbors  = (int*)   alloc((size_t)NROWS * NNB * 4);
    __bf16* Ah   = (__bf16*)alloc((size_t)NROWS * KP1 * 2);
    __bf16* Al   = (__bf16*)alloc((size_t)NROWS * KP1 * 2);
    __bf16* W1th = (__bf16*)alloc((size_t)HDIM * KP1 * 2);
    __bf16* W1tl = (__bf16*)alloc((size_t)HDIM * KP1 * 2);
    __bf16* W2th = (__bf16*)alloc((size_t)HDIM * HDIM * 2);
    __bf16* W2tl = (__bf16*)alloc((size_t)HDIM * HDIM * 2);
    __bf16* h1h  = (__bf16*)alloc((size_t)NROWS * HDIM * 2);
    __bf16* h1l  = (__bf16*)alloc((size_t)NROWS * HDIM * 2);
    float*  h2   = (float*) alloc((size_t)NROWS * HDIM * 4);

    k_topk<<<NROWS / 4, 256, 0, stream>>>(beta, total_beta, tasks);
    k_nbrs<<<NROWS / 4, 256, 0, stream>>>(total_beta, tasks, neighbors);
    k_build_inputs<<<NROWS, 256, 0, stream>>>(beta, actions, power, prev, tasks,
                                              neighbors, Ah, Al);
    {
        int n1 = HDIM * KP1;
        k_prep_w<<<(n1 + 255) / 256, 256, 0, stream>>>(W1, W1th, W1tl, INDIM, HDIM, KP1);
        int n2 = HDIM * HDIM;
        k_prep_w<<<(n2 + 255) / 256, 256, 0, stream>>>(W2, W2th, W2tl, HDIM, HDIM, HDIM);
    }
    k_gemm_tri<KP1, true><<<800, 128, 0, stream>>>(Ah, Al, W1th, W1tl, b1, h1h, h1l, nullptr);
    k_gemm_tri<HDIM, false><<<800, 128, 0, stream>>>(h1h, h1l, W2th, W2tl, nullptr,
                                                     nullptr, nullptr, h2);
    k_out<<<NROWS / 4, 256, 0, stream>>>(h2, b2, W3, b3, out);
}

// Round 6
// 300.314 us; speedup vs baseline: 1.9050x; 1.2433x over previous
//
#include <hip/hip_runtime.h>
#include <math.h>

#define NB 8
#define NT 32
#define NAG 50
#define MTASK 100
#define MTOP 10
#define NNB 10
#define LDIM 5
#define HDIM 512
#define INDIM 1610
#define KP1 1664            // INDIM padded to multiple of 64
#define NKT1 (KP1/32)       // 52 k-chunks
#define NKH1 (NKT1/2)       // 26 per split-K half
#define NKT2 (HDIM/32)      // 16
#define NKH2 (NKT2/2)       // 8
#define NROWS (NB*NT*NAG)   // 12800
#define NOUT (MTOP+1)       // 11
#define PLANE ((size_t)NROWS * HDIM)

typedef float f32x4 __attribute__((ext_vector_type(4)));
typedef __bf16 bf16x8 __attribute__((ext_vector_type(8)));

__device__ __forceinline__ void gload16(const __bf16* g, __bf16* l) {
    __builtin_amdgcn_global_load_lds(
        (__attribute__((address_space(1))) void*)(g),
        (__attribute__((address_space(3))) void*)(l), 16, 0, 0);
}

// Tiled operand layout ("LDS image"): elem (row, c) of a [rows][KP] matrix lives at
//   ((rowblk*NKT + kt)*4 + kc)*512 + (row&63)*8 + e
// where rowblk=row>>6, kt=c>>5, kc=(c>>3)&3, e=c&7.
// One global_load_lds of 64 lanes x 16B then covers [kc][64 rows][8] contiguously.

// ---------------- top-10 tasks, wave per row ----------------
__global__ __launch_bounds__(256) void k_topk(const float* __restrict__ beta,
                                              float* __restrict__ total_beta,
                                              int* __restrict__ tasks) {
    int wid = threadIdx.x >> 6, lane = threadIdx.x & 63;
    int row = blockIdx.x * 4 + wid;
    const float* bp = beta + (size_t)row * MTASK * LDIM;
    float v1, v2 = -INFINITY;
    {
        const float* p = bp + lane * LDIM;
        v1 = p[0] + p[1] + p[2] + p[3] + p[4];
        total_beta[(size_t)row * MTASK + lane] = v1;
    }
    if (lane + 64 < MTASK) {
        const float* p = bp + (lane + 64) * LDIM;
        v2 = p[0] + p[1] + p[2] + p[3] + p[4];
        total_beta[(size_t)row * MTASK + lane + 64] = v2;
    }
    for (int k = 0; k < MTOP; ++k) {
        float v; int idx;
        if (v1 >= v2) { v = v1; idx = lane; } else { v = v2; idx = lane + 64; }
        #pragma unroll
        for (int m = 1; m < 64; m <<= 1) {
            float vo = __shfl_xor(v, m, 64);
            int io = __shfl_xor(idx, m, 64);
            if (vo > v || (vo == v && io < idx)) { v = vo; idx = io; }
        }
        if (lane == 0) tasks[row * MTOP + k] = idx;
        if (idx == lane) v1 = -INFINITY;
        else if (idx == lane + 64) v2 = -INFINITY;
    }
}

// ---------------- neighbors, wave per row ----------------
__global__ __launch_bounds__(256) void k_nbrs(const float* __restrict__ total_beta,
                                              const int* __restrict__ tasks,
                                              int* __restrict__ neighbors) {
    int wid = threadIdx.x >> 6, lane = threadIdx.x & 63;
    int row = blockIdx.x * 4 + wid;
    int bt = row / NAG, i = row - bt * NAG;
    int tk[MTOP];
    #pragma unroll
    for (int k = 0; k < MTOP; ++k) tk[k] = tasks[row * MTOP + k];
    float v1 = -INFINITY;
    if (lane < NAG) {
        const float* tba = total_beta + ((size_t)bt * NAG + lane) * MTASK;
        float mx = -INFINITY;
        #pragma unroll
        for (int k = 0; k < MTOP; ++k) mx = fmaxf(mx, tba[tk[k]]);
        v1 = (lane == i) ? -INFINITY : mx;
    }
    for (int k = 0; k < NNB; ++k) {
        float v = v1; int idx = lane;
        #pragma unroll
        for (int m = 1; m < 64; m <<= 1) {
            float vo = __shfl_xor(v, m, 64);
            int io = __shfl_xor(idx, m, 64);
            if (vo > v || (vo == v && io < idx)) { v = vo; idx = io; }
        }
        if (lane == 0) neighbors[row * NNB + k] = idx;
        if (idx == lane) v1 = -INFINITY;
    }
}

// ---------------- build inputs as split bf16, TILED layout, block per row ----------------
__global__ void k_build_inputs(const float* __restrict__ beta,
                               const float* __restrict__ actions,
                               const float* __restrict__ power,
                               const int* __restrict__ prev,
                               const int* __restrict__ tasks,
                               const int* __restrict__ neighbors,
                               __bf16* __restrict__ Ah, __bf16* __restrict__ Al) {
    int row = blockIdx.x;
    int bt = row / NAG;
    __shared__ int tk[MTOP], nb[NNB], pa[NNB];
    __shared__ float pw[NNB];
    if (threadIdx.x < MTOP) tk[threadIdx.x] = tasks[row * MTOP + threadIdx.x];
    if (threadIdx.x >= 32 && threadIdx.x < 32 + NNB) {
        int j = threadIdx.x - 32;
        int nbj = neighbors[row * NNB + j];
        nb[j] = nbj;
        pa[j] = prev[bt * NAG + nbj];
        pw[j] = power[bt * NAG + nbj];
    }
    __syncthreads();
    int t = threadIdx.x;
    if (t < KP1 / 8) {   // 208 octets
        __bf16 h8[8], l8[8];
        #pragma unroll
        for (int e = 0; e < 8; ++e) {
            int c = t * 8 + e;
            float f = 0.f;
            if (c < 500) {
                int k = c / 50, r2 = c - k * 50, j = r2 / 5, l = r2 - j * 5;
                f = beta[(((size_t)bt * NAG + nb[j]) * MTASK + tk[k]) * LDIM + l];
            } else if (c < 1500) {
                int r2 = c - 500, j = r2 / MTASK, m = r2 - j * MTASK;
                f = actions[((size_t)bt * NAG + nb[j]) * MTASK + m];
            } else if (c < 1510) {
                f = pw[c - 1500];
            } else if (c < 1610) {
                int r2 = c - 1510, k = r2 / NNB, j = r2 - k * NNB;
                f = (tk[k] == pa[j]) ? 1.f : 0.f;
            }
            __bf16 h = (__bf16)f;
            h8[e] = h;
            l8[e] = (__bf16)(f - (float)h);
        }
        int rb = row >> 6, r = row & 63, kt = t >> 2, kc = t & 3;
        size_t off = ((size_t)(rb * NKT1 + kt) * 4 + kc) * 512 + r * 8;
        *(bf16x8*)&Ah[off] = *(bf16x8*)h8;
        *(bf16x8*)&Al[off] = *(bf16x8*)l8;
    }
}

// ---------------- weight prep: W[K][N] -> tiled split [N-rows][KP], LDS transpose ----------------
__global__ __launch_bounds__(256) void k_prep_wt(const float* __restrict__ W,
                                                 __bf16* __restrict__ Th,
                                                 __bf16* __restrict__ Tl,
                                                 int K, int N, int NKT) {
    int kp0 = blockIdx.x * 64, n0 = blockIdx.y * 64;
    __shared__ float lds[64][65];
    int t = threadIdx.x;
    int cc = t & 63, r0 = t >> 6;
    #pragma unroll
    for (int i = 0; i < 16; ++i) {
        int rr = r0 + i * 4;
        int kp = kp0 + rr;
        lds[rr][cc] = (kp < K) ? W[(size_t)kp * N + n0 + cc] : 0.f;
    }
    __syncthreads();
    int nblk = n0 >> 6;
    #pragma unroll
    for (int s = 0; s < 2; ++s) {
        int o = t + s * 256;
        int rn = o & 63, ko = o >> 6;           // ko in [0,8)
        int kp = kp0 + ko * 8;
        int kt = kp >> 5, kc = (kp >> 3) & 3;
        __bf16 h8[8], l8[8];
        #pragma unroll
        for (int e = 0; e < 8; ++e) {
            float f = lds[ko * 8 + e][rn];
            __bf16 h = (__bf16)f;
            h8[e] = h;
            l8[e] = (__bf16)(f - (float)h);
        }
        size_t off = ((size_t)(nblk * NKT + kt) * 4 + kc) * 512 + rn * 8;
        *(bf16x8*)&Th[off] = *(bf16x8*)h8;
        *(bf16x8*)&Tl[off] = *(bf16x8*)l8;
    }
}

// ---------------- split-bf16 MFMA GEMM, split-K=2, sequential 3-pass ----------------
// 128x128 tile, 4 waves, BK=32, 32KB LDS dbuf. grid 800 = 2 halves x 100 m x 4 n.
// XCD swizzle: XCDs 0-3 get half 0, XCDs 4-7 half 1 (each half's B stays L2-hot).
template<int NKT, int NKH>
__global__ __launch_bounds__(256, 2) void k_gemm_sk(
    const __bf16* __restrict__ Ahp, const __bf16* __restrict__ Alp,
    const __bf16* __restrict__ Bhp, const __bf16* __restrict__ Blp,
    float* __restrict__ P) {
    __shared__ __align__(16) __bf16 sA[2][4096];
    __shared__ __align__(16) __bf16 sB[2][4096];
    int tid = threadIdx.x, wid = tid >> 6, lane = tid & 63;
    int id = blockIdx.x;                        // 0..799
    int swz = (id & 7) * 100 + (id >> 3);       // bijective: 800 % 8 == 0
    int half = swz / 400;
    int rem = swz - half * 400;
    int nt = rem & 3, mt = rem >> 2;
    int koff = half * NKH;

    auto stage = [&](int kt3, int buf) {
        int p = kt3 / NKH;
        int kk = kt3 - p * NKH + koff;
        const __bf16* A = (p == 1) ? Alp : Ahp;
        const __bf16* Bq = (p == 2) ? Blp : Bhp;
        #pragma unroll
        for (int j = 0; j < 4; ++j) {
            int i = wid + 4 * j;
            int op = i >> 3, q = (i >> 2) & 1, kc = i & 3;
            if (op == 0) {
                int rb = 2 * mt + q;
                gload16(A + ((size_t)(rb * NKT + kk) * 4 + kc) * 512 + lane * 8,
                        &sA[buf][(kc * 128 + q * 64) * 8]);
            } else {
                int nb = 2 * nt + q;
                gload16(Bq + ((size_t)(nb * NKT + kk) * 4 + kc) * 512 + lane * 8,
                        &sB[buf][(kc * 128 + q * 64) * 8]);
            }
        }
    };

    int wr = wid >> 1, wc = wid & 1;
    int lrow = lane & 15, lk = lane >> 4;
    int aoff = (lk * 128 + wr * 64 + lrow) * 8;
    int boff = (lk * 128 + wc * 64 + lrow) * 8;
    f32x4 acc[4][4] = {};

    constexpr int NK3 = 3 * NKH;
    stage(0, 0);
    for (int kt3 = 0; kt3 < NK3; ++kt3) {
        int buf = kt3 & 1;
        __syncthreads();
        if (kt3 + 1 < NK3) stage(kt3 + 1, buf ^ 1);
        bf16x8 af[4], bfr[4];
        #pragma unroll
        for (int i = 0; i < 4; ++i) af[i] = *(const bf16x8*)&sA[buf][aoff + i * 128];
        #pragma unroll
        for (int j = 0; j < 4; ++j) bfr[j] = *(const bf16x8*)&sB[buf][boff + j * 128];
        #pragma unroll
        for (int i = 0; i < 4; ++i)
            #pragma unroll
            for (int j = 0; j < 4; ++j)
                acc[i][j] = __builtin_amdgcn_mfma_f32_16x16x32_bf16(af[i], bfr[j], acc[i][j], 0, 0, 0);
    }

    float* pout = P + (size_t)half * PLANE;
    #pragma unroll
    for (int i = 0; i < 4; ++i) {
        int mrow = mt * 128 + wr * 64 + i * 16 + lk * 4;
        #pragma unroll
        for (int j = 0; j < 4; ++j) {
            int n = nt * 128 + wc * 64 + j * 16 + lrow;
            #pragma unroll
            for (int r = 0; r < 4; ++r)
                pout[(size_t)(mrow + r) * HDIM + n] = acc[i][j][r];
        }
    }
}

// ---------------- combine GEMM1 halves -> relu -> split bf16 tiled (feeds GEMM2) ----------------
__global__ void k_combine1(const float* __restrict__ P, const float* __restrict__ b1,
                           __bf16* __restrict__ h1h, __bf16* __restrict__ h1l) {
    int idx = blockIdx.x * 256 + threadIdx.x;   // 819200
    int row = idx >> 6, o = idx & 63;
    int n0 = o * 8;
    const float* p0 = P + (size_t)row * HDIM + n0;
    const float* p1 = p0 + PLANE;
    f32x4 a0 = *(const f32x4*)p0, a1 = *(const f32x4*)(p0 + 4);
    f32x4 c0 = *(const f32x4*)p1, c1 = *(const f32x4*)(p1 + 4);
    f32x4 b0 = *(const f32x4*)&b1[n0], b1v = *(const f32x4*)&b1[n0 + 4];
    __bf16 h8[8], l8[8];
    #pragma unroll
    for (int i = 0; i < 4; ++i) {
        float f = fmaxf(a0[i] + c0[i] + b0[i], 0.f);
        __bf16 h = (__bf16)f;
        h8[i] = h; l8[i] = (__bf16)(f - (float)h);
        f = fmaxf(a1[i] + c1[i] + b1v[i], 0.f);
        h = (__bf16)f;
        h8[4 + i] = h; l8[4 + i] = (__bf16)(f - (float)h);
    }
    int rb = row >> 6, r = row & 63, kt = o >> 2, kc = o & 3;
    size_t off = ((size_t)(rb * NKT2 + kt) * 4 + kc) * 512 + r * 8;
    *(bf16x8*)&h1h[off] = *(bf16x8*)h8;
    *(bf16x8*)&h1l[off] = *(bf16x8*)l8;
}

// ---------------- output: combine GEMM2 halves + b2, relu, @W3 + b3 ; wave per row ----------------
__global__ __launch_bounds__(256) void k_out(const float* __restrict__ P,
                                             const float* __restrict__ b2,
                                             const float* __restrict__ W3,
                                             const float* __restrict__ b3,
                                             float* __restrict__ out) {
    int wid = threadIdx.x >> 6, lane = threadIdx.x & 63;
    int row = blockIdx.x * 4 + wid;
    const float* p0 = P + (size_t)row * HDIM + lane * 8;
    const float* p1 = p0 + PLANE;
    f32x4 a0 = *(const f32x4*)p0, a1 = *(const f32x4*)(p0 + 4);
    f32x4 c0 = *(const f32x4*)p1, c1 = *(const f32x4*)(p1 + 4);
    f32x4 b0 = *(const f32x4*)&b2[lane * 8], b1v = *(const f32x4*)&b2[lane * 8 + 4];
    float h[8];
    #pragma unroll
    for (int i = 0; i < 4; ++i) {
        h[i] = fmaxf(a0[i] + c0[i] + b0[i], 0.f);
        h[4 + i] = fmaxf(a1[i] + c1[i] + b1v[i], 0.f);
    }
    float acc[NOUT];
    #pragma unroll
    for (int n = 0; n < NOUT; ++n) acc[n] = 0.f;
    int k0 = lane * 8;
    #pragma unroll
    for (int i = 0; i < 8; ++i) {
        float hv = h[i];
        const float* w = W3 + (size_t)(k0 + i) * NOUT;
        #pragma unroll
        for (int n = 0; n < NOUT; ++n) acc[n] += hv * w[n];
    }
    #pragma unroll
    for (int off = 32; off >= 1; off >>= 1)
        #pragma unroll
        for (int n = 0; n < NOUT; ++n) acc[n] += __shfl_down(acc[n], off, 64);
    if (lane == 0) {
        #pragma unroll
        for (int n = 0; n < NOUT; ++n) out[(size_t)row * NOUT + n] = acc[n] + b3[n];
    }
}

extern "C" void kernel_launch(void* const* d_in, const int* in_sizes, int n_in,
                              void* d_out, int out_size, void* d_ws, size_t ws_size,
                              hipStream_t stream) {
    const float* beta    = (const float*)d_in[0];
    const float* actions = (const float*)d_in[1];
    const float* power   = (const float*)d_in[2];
    const int*   prev    = (const int*)d_in[3];
    const float* W1      = (const float*)d_in[4];
    const float* b1      = (const float*)d_in[5];
    const float* W2      = (const float*)d_in[6];
    const float* b2      = (const float*)d_in[7];
    const float* W3      = (const float*)d_in[8];
    const float* b3      = (const float*)d_in[9];
    float* out = (float*)d_out;

    char* ws = (char*)d_ws;
    size_t off = 0;
    auto alloc = [&](size_t bytes) { void* p = ws + off; off += (bytes + 255) & ~(size_t)255; return p; };
    float*  total_beta = (float*) alloc((size_t)NROWS * MTASK * 4);
    int*    tasks      = (int*)   alloc((size_t)NROWS * MTOP * 4);
    int*    neighbors  = (int*)   alloc((size_t)NROWS * NNB * 4);
    __bf16* Ah   = (__bf16*)alloc((size_t)NROWS * KP1 * 2);
    __bf16* Al   = (__bf16*)alloc((size_t)NROWS * KP1 * 2);
    __bf16* W1th = (__bf16*)alloc((size_t)HDIM * KP1 * 2);
    __bf16* W1tl = (__bf16*)alloc((size_t)HDIM * KP1 * 2);
    __bf16* W2th = (__bf16*)alloc((size_t)HDIM * HDIM * 2);
    __bf16* W2tl = (__bf16*)alloc((size_t)HDIM * HDIM * 2);
    __bf16* h1h  = (__bf16*)alloc((size_t)NROWS * HDIM * 2);
    __bf16* h1l  = (__bf16*)alloc((size_t)NROWS * HDIM * 2);
    float*  P    = (float*) alloc(2 * PLANE * 4);   // 105 MB, reused by GEMM2

    k_topk<<<NROWS / 4, 256, 0, stream>>>(beta, total_beta, tasks);
    k_nbrs<<<NROWS / 4, 256, 0, stream>>>(total_beta, tasks, neighbors);
    k_build_inputs<<<NROWS, 256, 0, stream>>>(beta, actions, power, prev, tasks,
                                              neighbors, Ah, Al);
    {
        dim3 gp1(KP1 / 64, HDIM / 64);
        k_prep_wt<<<gp1, 256, 0, stream>>>(W1, W1th, W1tl, INDIM, HDIM, NKT1);
        dim3 gp2(HDIM / 64, HDIM / 64);
        k_prep_wt<<<gp2, 256, 0, stream>>>(W2, W2th, W2tl, HDIM, HDIM, NKT2);
    }
    k_gemm_sk<NKT1, NKH1><<<800, 256, 0, stream>>>(Ah, Al, W1th, W1tl, P);
    k_combine1<<<(int)(PLANE / 8 / 256), 256, 0, stream>>>(P, b1, h1h, h1l);
    k_gemm_sk<NKT2, NKH2><<<800, 256, 0, stream>>>(h1h, h1l, W2th, W2tl, P);
    k_out<<<NROWS / 4, 256, 0, stream>>>(P, b2, W3, b3, out);
}

// Round 7
// 267.269 us; speedup vs baseline: 2.1406x; 1.1236x over previous
//
#include <hip/hip_runtime.h>
#include <math.h>

#define NB 8
#define NT 32
#define NAG 50
#define MTASK 100
#define MTOP 10
#define NNB 10
#define LDIM 5
#define HDIM 512
#define INDIM 1610
#define KP1 1664            // INDIM padded to multiple of 64
#define NKT1 (KP1/32)       // 52 k-chunks
#define NKH1 (NKT1/2)       // 26 per split-K half
#define NKT2 (HDIM/32)      // 16
#define NKH2 (NKT2/2)       // 8
#define NROWS (NB*NT*NAG)   // 12800
#define NOUT (MTOP+1)       // 11
#define PLANE ((size_t)NROWS * HDIM)

typedef float f32x4 __attribute__((ext_vector_type(4)));
typedef __bf16 bf16x8 __attribute__((ext_vector_type(8)));

__device__ __forceinline__ void gload16(const __bf16* g, __bf16* l) {
    __builtin_amdgcn_global_load_lds(
        (__attribute__((address_space(1))) void*)(g),
        (__attribute__((address_space(3))) void*)(l), 16, 0, 0);
}

// Tiled operand layout: elem (row, c) of a [rows][KP] matrix lives at
//   (rowblk*NKT*4 + octet)*512 + (row&63)*8 + (c&7),  octet = c>>3 within K... (kt*4+kc)
// i.e. one 1KB run holds [octet][64 rows][8 elems] -> global_load_lds reads it whole.

// ---------------- top-10 tasks, wave per row ----------------
__global__ __launch_bounds__(256) void k_topk(const float* __restrict__ beta,
                                              float* __restrict__ total_beta,
                                              int* __restrict__ tasks) {
    int wid = threadIdx.x >> 6, lane = threadIdx.x & 63;
    int row = blockIdx.x * 4 + wid;
    const float* bp = beta + (size_t)row * MTASK * LDIM;
    float v1, v2 = -INFINITY;
    {
        const float* p = bp + lane * LDIM;
        v1 = p[0] + p[1] + p[2] + p[3] + p[4];
        total_beta[(size_t)row * MTASK + lane] = v1;
    }
    if (lane + 64 < MTASK) {
        const float* p = bp + (lane + 64) * LDIM;
        v2 = p[0] + p[1] + p[2] + p[3] + p[4];
        total_beta[(size_t)row * MTASK + lane + 64] = v2;
    }
    for (int k = 0; k < MTOP; ++k) {
        float v; int idx;
        if (v1 >= v2) { v = v1; idx = lane; } else { v = v2; idx = lane + 64; }
        #pragma unroll
        for (int m = 1; m < 64; m <<= 1) {
            float vo = __shfl_xor(v, m, 64);
            int io = __shfl_xor(idx, m, 64);
            if (vo > v || (vo == v && io < idx)) { v = vo; idx = io; }
        }
        if (lane == 0) tasks[row * MTOP + k] = idx;
        if (idx == lane) v1 = -INFINITY;
        else if (idx == lane + 64) v2 = -INFINITY;
    }
}

// ---------------- neighbors, wave per row ----------------
__global__ __launch_bounds__(256) void k_nbrs(const float* __restrict__ total_beta,
                                              const int* __restrict__ tasks,
                                              int* __restrict__ neighbors) {
    int wid = threadIdx.x >> 6, lane = threadIdx.x & 63;
    int row = blockIdx.x * 4 + wid;
    int bt = row / NAG, i = row - bt * NAG;
    int tk[MTOP];
    #pragma unroll
    for (int k = 0; k < MTOP; ++k) tk[k] = tasks[row * MTOP + k];
    float v1 = -INFINITY;
    if (lane < NAG) {
        const float* tba = total_beta + ((size_t)bt * NAG + lane) * MTASK;
        float mx = -INFINITY;
        #pragma unroll
        for (int k = 0; k < MTOP; ++k) mx = fmaxf(mx, tba[tk[k]]);
        v1 = (lane == i) ? -INFINITY : mx;
    }
    for (int k = 0; k < NNB; ++k) {
        float v = v1; int idx = lane;
        #pragma unroll
        for (int m = 1; m < 64; m <<= 1) {
            float vo = __shfl_xor(v, m, 64);
            int io = __shfl_xor(idx, m, 64);
            if (vo > v || (vo == v && io < idx)) { v = vo; idx = io; }
        }
        if (lane == 0) neighbors[row * NNB + k] = idx;
        if (idx == lane) v1 = -INFINITY;
    }
}

// ---------------- build inputs v2: 16 rows/block, coalesced 256B tiled writes ----------------
__global__ __launch_bounds__(256) void k_build_inputs(
    const float* __restrict__ beta, const float* __restrict__ actions,
    const float* __restrict__ power, const int* __restrict__ prev,
    const int* __restrict__ tasks, const int* __restrict__ neighbors,
    __bf16* __restrict__ Ah, __bf16* __restrict__ Al) {
    int b = blockIdx.x;                 // 0..799, rows [b*16, b*16+16)
    int t = threadIdx.x;
    __shared__ int tkv[16][MTOP], nbv[16][NNB], pav[16][NNB];
    __shared__ float pwv[16][NNB];
    if (t < 160) {
        int lr = t / 10, j = t - lr * 10;
        int row = b * 16 + lr;
        int bt = row / NAG;
        int nbj = neighbors[row * NNB + j];
        nbv[lr][j] = nbj;
        pav[lr][j] = prev[bt * NAG + nbj];
        pwv[lr][j] = power[bt * NAG + nbj];
        tkv[lr][j] = tasks[row * MTOP + j];
    }
    __syncthreads();
    int l = t & 15, og = t >> 4;        // l: row-in-block, og: octet group
    int row = b * 16 + l;
    int bt = row / NAG;
    int rb = row >> 6, rlo = row & 63;
    const float* bsl = beta + (size_t)bt * NAG * MTASK * LDIM;
    const float* asl = actions + (size_t)bt * NAG * MTASK;
    #pragma unroll
    for (int s = 0; s < 13; ++s) {      // 13*16 = 208 octets
        int o = og + 16 * s;
        __bf16 h8[8], l8[8];
        #pragma unroll
        for (int e = 0; e < 8; ++e) {
            int c = o * 8 + e;
            float f = 0.f;
            if (c < 500) {
                int k = c / 50, r2 = c - k * 50, j = r2 / 5, ll = r2 - j * 5;
                f = bsl[((size_t)nbv[l][j] * MTASK + tkv[l][k]) * LDIM + ll];
            } else if (c < 1500) {
                int r2 = c - 500, j = r2 / MTASK, m = r2 - j * MTASK;
                f = asl[(size_t)nbv[l][j] * MTASK + m];
            } else if (c < 1510) {
                f = pwv[l][c - 1500];
            } else if (c < 1610) {
                int r2 = c - 1510, k = r2 / NNB, j = r2 - k * NNB;
                f = (tkv[l][k] == pav[l][j]) ? 1.f : 0.f;
            }
            __bf16 h = (__bf16)f;
            h8[e] = h;
            l8[e] = (__bf16)(f - (float)h);
        }
        size_t off = ((size_t)rb * NKT1 * 4 + o) * 512 + rlo * 8;
        *(bf16x8*)&Ah[off] = *(bf16x8*)h8;
        *(bf16x8*)&Al[off] = *(bf16x8*)l8;
    }
}

// ---------------- weight prep: W[K][N] -> tiled split [N-rows][KP], LDS transpose ----------------
__global__ __launch_bounds__(256) void k_prep_wt(const float* __restrict__ W,
                                                 __bf16* __restrict__ Th,
                                                 __bf16* __restrict__ Tl,
                                                 int K, int N, int NKT) {
    int kp0 = blockIdx.x * 64, n0 = blockIdx.y * 64;
    __shared__ float lds[64][65];
    int t = threadIdx.x;
    int cc = t & 63, r0 = t >> 6;
    #pragma unroll
    for (int i = 0; i < 16; ++i) {
        int rr = r0 + i * 4;
        int kp = kp0 + rr;
        lds[rr][cc] = (kp < K) ? W[(size_t)kp * N + n0 + cc] : 0.f;
    }
    __syncthreads();
    int nblk = n0 >> 6;
    #pragma unroll
    for (int s = 0; s < 2; ++s) {
        int o = t + s * 256;
        int rn = o & 63, ko = o >> 6;
        int kp = kp0 + ko * 8;
        int kt = kp >> 5, kc = (kp >> 3) & 3;
        __bf16 h8[8], l8[8];
        #pragma unroll
        for (int e = 0; e < 8; ++e) {
            float f = lds[ko * 8 + e][rn];
            __bf16 h = (__bf16)f;
            h8[e] = h;
            l8[e] = (__bf16)(f - (float)h);
        }
        size_t off = ((size_t)(nblk * NKT + kt) * 4 + kc) * 512 + rn * 8;
        *(bf16x8*)&Th[off] = *(bf16x8*)h8;
        *(bf16x8*)&Tl[off] = *(bf16x8*)l8;
    }
}

// ---------------- split-bf16 MFMA GEMM, split-K=2, sequential 3-pass ----------------
template<int NKT, int NKH>
__global__ __launch_bounds__(256, 2) void k_gemm_sk(
    const __bf16* __restrict__ Ahp, const __bf16* __restrict__ Alp,
    const __bf16* __restrict__ Bhp, const __bf16* __restrict__ Blp,
    float* __restrict__ P) {
    __shared__ __align__(16) __bf16 sA[2][4096];
    __shared__ __align__(16) __bf16 sB[2][4096];
    int tid = threadIdx.x, wid = tid >> 6, lane = tid & 63;
    int id = blockIdx.x;
    int swz = (id & 7) * 100 + (id >> 3);       // bijective: 800 % 8 == 0
    int half = swz / 400;
    int rem = swz - half * 400;
    int nt = rem & 3, mt = rem >> 2;
    int koff = half * NKH;

    auto stage = [&](int kt3, int buf) {
        int p = kt3 / NKH;
        int kk = kt3 - p * NKH + koff;
        const __bf16* A = (p == 1) ? Alp : Ahp;
        const __bf16* Bq = (p == 2) ? Blp : Bhp;
        #pragma unroll
        for (int j = 0; j < 4; ++j) {
            int i = wid + 4 * j;
            int op = i >> 3, q = (i >> 2) & 1, kc = i & 3;
            if (op == 0) {
                int rb = 2 * mt + q;
                gload16(A + ((size_t)(rb * NKT + kk) * 4 + kc) * 512 + lane * 8,
                        &sA[buf][(kc * 128 + q * 64) * 8]);
            } else {
                int nb = 2 * nt + q;
                gload16(Bq + ((size_t)(nb * NKT + kk) * 4 + kc) * 512 + lane * 8,
                        &sB[buf][(kc * 128 + q * 64) * 8]);
            }
        }
    };

    int wr = wid >> 1, wc = wid & 1;
    int lrow = lane & 15, lk = lane >> 4;
    int aoff = (lk * 128 + wr * 64 + lrow) * 8;
    int boff = (lk * 128 + wc * 64 + lrow) * 8;
    f32x4 acc[4][4] = {};

    constexpr int NK3 = 3 * NKH;
    stage(0, 0);
    for (int kt3 = 0; kt3 < NK3; ++kt3) {
        int buf = kt3 & 1;
        __syncthreads();
        if (kt3 + 1 < NK3) stage(kt3 + 1, buf ^ 1);
        bf16x8 af[4], bfr[4];
        #pragma unroll
        for (int i = 0; i < 4; ++i) af[i] = *(const bf16x8*)&sA[buf][aoff + i * 128];
        #pragma unroll
        for (int j = 0; j < 4; ++j) bfr[j] = *(const bf16x8*)&sB[buf][boff + j * 128];
        #pragma unroll
        for (int i = 0; i < 4; ++i)
            #pragma unroll
            for (int j = 0; j < 4; ++j)
                acc[i][j] = __builtin_amdgcn_mfma_f32_16x16x32_bf16(af[i], bfr[j], acc[i][j], 0, 0, 0);
    }

    float* pout = P + (size_t)half * PLANE;
    #pragma unroll
    for (int i = 0; i < 4; ++i) {
        int mrow = mt * 128 + wr * 64 + i * 16 + lk * 4;
        #pragma unroll
        for (int j = 0; j < 4; ++j) {
            int n = nt * 128 + wc * 64 + j * 16 + lrow;
            #pragma unroll
            for (int r = 0; r < 4; ++r)
                pout[(size_t)(mrow + r) * HDIM + n] = acc[i][j][r];
        }
    }
}

// ---------------- combine1 v2: coalesced reads, LDS transpose, coalesced tiled writes ----------------
__global__ __launch_bounds__(256) void k_combine1(const float* __restrict__ P,
                                                  const float* __restrict__ b1,
                                                  __bf16* __restrict__ h1h,
                                                  __bf16* __restrict__ h1l) {
    int b = blockIdx.x;                  // 0..799, rows [b*16, b*16+16)
    int t = threadIdx.x;
    __shared__ float lds[16][523];       // odd stride -> conflict-free transposed read
    int rb = b >> 2, q = b & 3;
    // read phase: coalesced f32x4 from both planes
    #pragma unroll
    for (int rep = 0; rep < 8; ++rep) {
        int g = rep * 1024 + t * 4;      // 0..8191
        int lr = g >> 9, col = g & 511;
        size_t base = (size_t)(b * 16 + lr) * HDIM + col;
        f32x4 a = *(const f32x4*)&P[base];
        f32x4 c = *(const f32x4*)&P[PLANE + base];
        f32x4 bv = *(const f32x4*)&b1[col];
        #pragma unroll
        for (int i = 0; i < 4; ++i)
            lds[lr][col + i] = fmaxf(a[i] + c[i] + bv[i], 0.f);
    }
    __syncthreads();
    // write phase: per octet o, 16 lanes write 256B contiguous
    int l = t & 15, og = t >> 4;
    #pragma unroll
    for (int s = 0; s < 4; ++s) {
        int o = og + 16 * s;             // 0..63
        __bf16 h8[8], l8[8];
        #pragma unroll
        for (int e = 0; e < 8; ++e) {
            float f = lds[l][o * 8 + e];
            __bf16 h = (__bf16)f;
            h8[e] = h;
            l8[e] = (__bf16)(f - (float)h);
        }
        size_t off = ((size_t)rb * 64 + o) * 512 + (q * 16 + l) * 8;
        *(bf16x8*)&h1h[off] = *(bf16x8*)h8;
        *(bf16x8*)&h1l[off] = *(bf16x8*)l8;
    }
}

// ---------------- output: combine GEMM2 halves + b2, relu, @W3 + b3 ; wave per row ----------------
__global__ __launch_bounds__(256) void k_out(const float* __restrict__ P,
                                             const float* __restrict__ b2,
                                             const float* __restrict__ W3,
                                             const float* __restrict__ b3,
                                             float* __restrict__ out) {
    int wid = threadIdx.x >> 6, lane = threadIdx.x & 63;
    int row = blockIdx.x * 4 + wid;
    const float* p0 = P + (size_t)row * HDIM + lane * 8;
    const float* p1 = p0 + PLANE;
    f32x4 a0 = *(const f32x4*)p0, a1 = *(const f32x4*)(p0 + 4);
    f32x4 c0 = *(const f32x4*)p1, c1 = *(const f32x4*)(p1 + 4);
    f32x4 b0 = *(const f32x4*)&b2[lane * 8], b1v = *(const f32x4*)&b2[lane * 8 + 4];
    float h[8];
    #pragma unroll
    for (int i = 0; i < 4; ++i) {
        h[i] = fmaxf(a0[i] + c0[i] + b0[i], 0.f);
        h[4 + i] = fmaxf(a1[i] + c1[i] + b1v[i], 0.f);
    }
    float acc[NOUT];
    #pragma unroll
    for (int n = 0; n < NOUT; ++n) acc[n] = 0.f;
    int k0 = lane * 8;
    #pragma unroll
    for (int i = 0; i < 8; ++i) {
        float hv = h[i];
        const float* w = W3 + (size_t)(k0 + i) * NOUT;
        #pragma unroll
        for (int n = 0; n < NOUT; ++n) acc[n] += hv * w[n];
    }
    #pragma unroll
    for (int off = 32; off >= 1; off >>= 1)
        #pragma unroll
        for (int n = 0; n < NOUT; ++n) acc[n] += __shfl_down(acc[n], off, 64);
    if (lane == 0) {
        #pragma unroll
        for (int n = 0; n < NOUT; ++n) out[(size_t)row * NOUT + n] = acc[n] + b3[n];
    }
}

extern "C" void kernel_launch(void* const* d_in, const int* in_sizes, int n_in,
                              void* d_out, int out_size, void* d_ws, size_t ws_size,
                              hipStream_t stream) {
    const float* beta    = (const float*)d_in[0];
    const float* actions = (const float*)d_in[1];
    const float* power   = (const float*)d_in[2];
    const int*   prev    = (const int*)d_in[3];
    const float* W1      = (const float*)d_in[4];
    const float* b1      = (const float*)d_in[5];
    const float* W2      = (const float*)d_in[6];
    const float* b2      = (const float*)d_in[7];
    const float* W3      = (const float*)d_in[8];
    const float* b3      = (const float*)d_in[9];
    float* out = (float*)d_out;

    char* ws = (char*)d_ws;
    size_t off = 0;
    auto alloc = [&](size_t bytes) { void* p = ws + off; off += (bytes + 255) & ~(size_t)255; return p; };
    float*  total_beta = (float*) alloc((size_t)NROWS * MTASK * 4);
    int*    tasks      = (int*)   alloc((size_t)NROWS * MTOP * 4);
    int*    neighbors  = (int*)   alloc((size_t)NROWS * NNB * 4);
    __bf16* Ah   = (__bf16*)alloc((size_t)NROWS * KP1 * 2);
    __bf16* Al   = (__bf16*)alloc((size_t)NROWS * KP1 * 2);
    __bf16* W1th = (__bf16*)alloc((size_t)HDIM * KP1 * 2);
    __bf16* W1tl = (__bf16*)alloc((size_t)HDIM * KP1 * 2);
    __bf16* W2th = (__bf16*)alloc((size_t)HDIM * HDIM * 2);
    __bf16* W2tl = (__bf16*)alloc((size_t)HDIM * HDIM * 2);
    __bf16* h1h  = (__bf16*)alloc((size_t)NROWS * HDIM * 2);
    __bf16* h1l  = (__bf16*)alloc((size_t)NROWS * HDIM * 2);
    float*  P    = (float*) alloc(2 * PLANE * 4);

    k_topk<<<NROWS / 4, 256, 0, stream>>>(beta, total_beta, tasks);
    k_nbrs<<<NROWS / 4, 256, 0, stream>>>(total_beta, tasks, neighbors);
    k_build_inputs<<<NROWS / 16, 256, 0, stream>>>(beta, actions, power, prev, tasks,
                                                   neighbors, Ah, Al);
    {
        dim3 gp1(KP1 / 64, HDIM / 64);
        k_prep_wt<<<gp1, 256, 0, stream>>>(W1, W1th, W1tl, INDIM, HDIM, NKT1);
        dim3 gp2(HDIM / 64, HDIM / 64);
        k_prep_wt<<<gp2, 256, 0, stream>>>(W2, W2th, W2tl, HDIM, HDIM, NKT2);
    }
    k_gemm_sk<NKT1, NKH1><<<800, 256, 0, stream>>>(Ah, Al, W1th, W1tl, P);
    k_combine1<<<NROWS / 16, 256, 0, stream>>>(P, b1, h1h, h1l);
    k_gemm_sk<NKT2, NKH2><<<800, 256, 0, stream>>>(h1h, h1l, W2th, W2tl, P);
    k_out<<<NROWS / 4, 256, 0, stream>>>(P, b2, W3, b3, out);
}

// Round 8
// 239.705 us; speedup vs baseline: 2.3867x; 1.1150x over previous
//
#include <hip/hip_runtime.h>
#include <math.h>

#define NB 8
#define NT 32
#define NAG 50
#define MTASK 100
#define MTOP 10
#define NNB 10
#define LDIM 5
#define HDIM 512
#define INDIM 1610
#define KP1 1664            // INDIM padded to multiple of 64
#define NKT1 (KP1/32)       // 52 k-chunks
#define NKH1 (NKT1/2)       // 26 per split-K half
#define NKT2 (HDIM/32)      // 16
#define NKH2 (NKT2/2)       // 8
#define NROWS (NB*NT*NAG)   // 12800
#define NOUT (MTOP+1)       // 11
#define PLANE ((size_t)NROWS * HDIM)

typedef float f32x4 __attribute__((ext_vector_type(4)));
typedef __bf16 bf16x8 __attribute__((ext_vector_type(8)));

__device__ __forceinline__ void gload16(const __bf16* g, __bf16* l) {
    __builtin_amdgcn_global_load_lds(
        (__attribute__((address_space(1))) void*)(g),
        (__attribute__((address_space(3))) void*)(l), 16, 0, 0);
}

// Tiled operand layout: elem (row, c) of a [rows][KP] matrix lives at
//   (rowblk*NKT*4 + octet)*512 + (row&63)*8 + (c&7),  octet = (c>>5)*4 + ((c>>3)&3)
// One 1KB run holds [octet][64 rows][8 elems] -> one global_load_lds covers it.

// ---------------- top-10 tasks, wave per row ----------------
__global__ __launch_bounds__(256) void k_topk(const float* __restrict__ beta,
                                              float* __restrict__ total_beta,
                                              int* __restrict__ tasks) {
    int wid = threadIdx.x >> 6, lane = threadIdx.x & 63;
    int row = blockIdx.x * 4 + wid;
    const float* bp = beta + (size_t)row * MTASK * LDIM;
    float v1, v2 = -INFINITY;
    {
        const float* p = bp + lane * LDIM;
        v1 = p[0] + p[1] + p[2] + p[3] + p[4];
        total_beta[(size_t)row * MTASK + lane] = v1;
    }
    if (lane + 64 < MTASK) {
        const float* p = bp + (lane + 64) * LDIM;
        v2 = p[0] + p[1] + p[2] + p[3] + p[4];
        total_beta[(size_t)row * MTASK + lane + 64] = v2;
    }
    for (int k = 0; k < MTOP; ++k) {
        float v; int idx;
        if (v1 >= v2) { v = v1; idx = lane; } else { v = v2; idx = lane + 64; }
        #pragma unroll
        for (int m = 1; m < 64; m <<= 1) {
            float vo = __shfl_xor(v, m, 64);
            int io = __shfl_xor(idx, m, 64);
            if (vo > v || (vo == v && io < idx)) { v = vo; idx = io; }
        }
        if (lane == 0) tasks[row * MTOP + k] = idx;
        if (idx == lane) v1 = -INFINITY;
        else if (idx == lane + 64) v2 = -INFINITY;
    }
}

// ---------------- neighbors, wave per row ----------------
__global__ __launch_bounds__(256) void k_nbrs(const float* __restrict__ total_beta,
                                              const int* __restrict__ tasks,
                                              int* __restrict__ neighbors) {
    int wid = threadIdx.x >> 6, lane = threadIdx.x & 63;
    int row = blockIdx.x * 4 + wid;
    int bt = row / NAG, i = row - bt * NAG;
    int tk[MTOP];
    #pragma unroll
    for (int k = 0; k < MTOP; ++k) tk[k] = tasks[row * MTOP + k];
    float v1 = -INFINITY;
    if (lane < NAG) {
        const float* tba = total_beta + ((size_t)bt * NAG + lane) * MTASK;
        float mx = -INFINITY;
        #pragma unroll
        for (int k = 0; k < MTOP; ++k) mx = fmaxf(mx, tba[tk[k]]);
        v1 = (lane == i) ? -INFINITY : mx;
    }
    for (int k = 0; k < NNB; ++k) {
        float v = v1; int idx = lane;
        #pragma unroll
        for (int m = 1; m < 64; m <<= 1) {
            float vo = __shfl_xor(v, m, 64);
            int io = __shfl_xor(idx, m, 64);
            if (vo > v || (vo == v && io < idx)) { v = vo; idx = io; }
        }
        if (lane == 0) neighbors[row * NNB + k] = idx;
        if (idx == lane) v1 = -INFINITY;
    }
}

// ---------------- build inputs: 16 rows/block, coalesced 256B tiled writes ----------------
__global__ __launch_bounds__(256) void k_build_inputs(
    const float* __restrict__ beta, const float* __restrict__ actions,
    const float* __restrict__ power, const int* __restrict__ prev,
    const int* __restrict__ tasks, const int* __restrict__ neighbors,
    __bf16* __restrict__ Ah, __bf16* __restrict__ Al) {
    int b = blockIdx.x;                 // rows [b*16, b*16+16)
    int t = threadIdx.x;
    __shared__ int tkv[16][MTOP], nbv[16][NNB], pav[16][NNB];
    __shared__ float pwv[16][NNB];
    if (t < 160) {
        int lr = t / 10, j = t - lr * 10;
        int row = b * 16 + lr;
        int bt = row / NAG;
        int nbj = neighbors[row * NNB + j];
        nbv[lr][j] = nbj;
        pav[lr][j] = prev[bt * NAG + nbj];
        pwv[lr][j] = power[bt * NAG + nbj];
        tkv[lr][j] = tasks[row * MTOP + j];
    }
    __syncthreads();
    int l = t & 15, og = t >> 4;
    int row = b * 16 + l;
    int bt = row / NAG;
    int rb = row >> 6, rlo = row & 63;
    const float* bsl = beta + (size_t)bt * NAG * MTASK * LDIM;
    const float* asl = actions + (size_t)bt * NAG * MTASK;
    #pragma unroll
    for (int s = 0; s < 13; ++s) {      // 13*16 = 208 octets
        int o = og + 16 * s;
        __bf16 h8[8], l8[8];
        #pragma unroll
        for (int e = 0; e < 8; ++e) {
            int c = o * 8 + e;
            float f = 0.f;
            if (c < 500) {
                int k = c / 50, r2 = c - k * 50, j = r2 / 5, ll = r2 - j * 5;
                f = bsl[((size_t)nbv[l][j] * MTASK + tkv[l][k]) * LDIM + ll];
            } else if (c < 1500) {
                int r2 = c - 500, j = r2 / MTASK, m = r2 - j * MTASK;
                f = asl[(size_t)nbv[l][j] * MTASK + m];
            } else if (c < 1510) {
                f = pwv[l][c - 1500];
            } else if (c < 1610) {
                int r2 = c - 1510, k = r2 / NNB, j = r2 - k * NNB;
                f = (tkv[l][k] == pav[l][j]) ? 1.f : 0.f;
            }
            __bf16 h = (__bf16)f;
            h8[e] = h;
            l8[e] = (__bf16)(f - (float)h);
        }
        size_t off = ((size_t)rb * NKT1 * 4 + o) * 512 + rlo * 8;
        *(bf16x8*)&Ah[off] = *(bf16x8*)h8;
        *(bf16x8*)&Al[off] = *(bf16x8*)l8;
    }
}

// ---------------- weight prep: W[K][N] -> tiled hi-only [N-rows][KP] ----------------
__global__ __launch_bounds__(256) void k_prep_wt(const float* __restrict__ W,
                                                 __bf16* __restrict__ Th,
                                                 int K, int N, int NKT) {
    int kp0 = blockIdx.x * 64, n0 = blockIdx.y * 64;
    __shared__ float lds[64][65];
    int t = threadIdx.x;
    int cc = t & 63, r0 = t >> 6;
    #pragma unroll
    for (int i = 0; i < 16; ++i) {
        int rr = r0 + i * 4;
        int kp = kp0 + rr;
        lds[rr][cc] = (kp < K) ? W[(size_t)kp * N + n0 + cc] : 0.f;
    }
    __syncthreads();
    int nblk = n0 >> 6;
    #pragma unroll
    for (int s = 0; s < 2; ++s) {
        int o = t + s * 256;
        int rn = o & 63, ko = o >> 6;
        int kp = kp0 + ko * 8;
        int kt = kp >> 5, kc = (kp >> 3) & 3;
        __bf16 h8[8];
        #pragma unroll
        for (int e = 0; e < 8; ++e) h8[e] = (__bf16)lds[ko * 8 + e][rn];
        size_t off = ((size_t)(nblk * NKT + kt) * 4 + kc) * 512 + rn * 8;
        *(bf16x8*)&Th[off] = *(bf16x8*)h8;
    }
}

// ---------------- 2-pass chunk-interleaved split-bf16 GEMM, split-K=2 ----------------
// Per K-step stage {Ah, Al, Bh} (24 gloads), fire 32 MFMA (AhBh + AlBh).
// 128x128 tile, 4 waves, 48KB LDS dbuf, grid 800 = 2 halves x 100m x 4n.
template<int NKT, int NKH>
__global__ __launch_bounds__(256, 3) void k_gemm_sk(
    const __bf16* __restrict__ Ahp, const __bf16* __restrict__ Alp,
    const __bf16* __restrict__ Bhp,
    float* __restrict__ P) {
    __shared__ __align__(16) __bf16 sAh[2][4096];
    __shared__ __align__(16) __bf16 sAl[2][4096];
    __shared__ __align__(16) __bf16 sB[2][4096];
    int tid = threadIdx.x, wid = tid >> 6, lane = tid & 63;
    int id = blockIdx.x;
    int swz = (id & 7) * 100 + (id >> 3);       // bijective: 800 % 8 == 0
    int half = swz / 400;
    int rem = swz - half * 400;
    int nt = rem & 3, mt = rem >> 2;
    int koff = half * NKH;

    auto stage = [&](int kk, int buf) {         // kk: absolute k-chunk
        #pragma unroll
        for (int j = 0; j < 6; ++j) {
            int seg = wid + 4 * j;              // 0..23
            int grp = seg >> 3;                 // 0:Ah 1:Al 2:Bh
            int s = seg & 7, q = s >> 2, kc = s & 3;
            int ldso = (kc * 128 + q * 64) * 8;
            if (grp == 0) {
                gload16(Ahp + ((size_t)((2 * mt + q) * NKT + kk) * 4 + kc) * 512 + lane * 8,
                        &sAh[buf][ldso]);
            } else if (grp == 1) {
                gload16(Alp + ((size_t)((2 * mt + q) * NKT + kk) * 4 + kc) * 512 + lane * 8,
                        &sAl[buf][ldso]);
            } else {
                gload16(Bhp + ((size_t)((2 * nt + q) * NKT + kk) * 4 + kc) * 512 + lane * 8,
                        &sB[buf][ldso]);
            }
        }
    };

    int wr = wid >> 1, wc = wid & 1;
    int lrow = lane & 15, lk = lane >> 4;
    int aoff = (lk * 128 + wr * 64 + lrow) * 8;
    int boff = (lk * 128 + wc * 64 + lrow) * 8;
    f32x4 acc[4][4] = {};

    stage(koff, 0);
    for (int kt = 0; kt < NKH; ++kt) {
        int buf = kt & 1;
        __syncthreads();
        if (kt + 1 < NKH) stage(koff + kt + 1, buf ^ 1);
        bf16x8 ah[4], al[4], bh[4];
        #pragma unroll
        for (int i = 0; i < 4; ++i) {
            ah[i] = *(const bf16x8*)&sAh[buf][aoff + i * 128];
            al[i] = *(const bf16x8*)&sAl[buf][aoff + i * 128];
        }
        #pragma unroll
        for (int j = 0; j < 4; ++j) bh[j] = *(const bf16x8*)&sB[buf][boff + j * 128];
        #pragma unroll
        for (int i = 0; i < 4; ++i)
            #pragma unroll
            for (int j = 0; j < 4; ++j) {
                acc[i][j] = __builtin_amdgcn_mfma_f32_16x16x32_bf16(ah[i], bh[j], acc[i][j], 0, 0, 0);
                acc[i][j] = __builtin_amdgcn_mfma_f32_16x16x32_bf16(al[i], bh[j], acc[i][j], 0, 0, 0);
            }
    }

    float* pout = P + (size_t)half * PLANE;
    #pragma unroll
    for (int i = 0; i < 4; ++i) {
        int mrow = mt * 128 + wr * 64 + i * 16 + lk * 4;
        #pragma unroll
        for (int j = 0; j < 4; ++j) {
            int n = nt * 128 + wc * 64 + j * 16 + lrow;
            #pragma unroll
            for (int r = 0; r < 4; ++r)
                pout[(size_t)(mrow + r) * HDIM + n] = acc[i][j][r];
        }
    }
}

// ---------------- combine1: coalesced reads, LDS transpose, coalesced tiled writes ----------------
__global__ __launch_bounds__(256) void k_combine1(const float* __restrict__ P,
                                                  const float* __restrict__ b1,
                                                  __bf16* __restrict__ h1h,
                                                  __bf16* __restrict__ h1l) {
    int b = blockIdx.x;                  // rows [b*16, b*16+16)
    int t = threadIdx.x;
    __shared__ float lds[16][523];
    int rb = b >> 2, q = b & 3;
    #pragma unroll
    for (int rep = 0; rep < 8; ++rep) {
        int g = rep * 1024 + t * 4;
        int lr = g >> 9, col = g & 511;
        size_t base = (size_t)(b * 16 + lr) * HDIM + col;
        f32x4 a = *(const f32x4*)&P[base];
        f32x4 c = *(const f32x4*)&P[PLANE + base];
        f32x4 bv = *(const f32x4*)&b1[col];
        #pragma unroll
        for (int i = 0; i < 4; ++i)
            lds[lr][col + i] = fmaxf(a[i] + c[i] + bv[i], 0.f);
    }
    __syncthreads();
    int l = t & 15, og = t >> 4;
    #pragma unroll
    for (int s = 0; s < 4; ++s) {
        int o = og + 16 * s;
        __bf16 h8[8], l8[8];
        #pragma unroll
        for (int e = 0; e < 8; ++e) {
            float f = lds[l][o * 8 + e];
            __bf16 h = (__bf16)f;
            h8[e] = h;
            l8[e] = (__bf16)(f - (float)h);
        }
        size_t off = ((size_t)rb * 64 + o) * 512 + (q * 16 + l) * 8;
        *(bf16x8*)&h1h[off] = *(bf16x8*)h8;
        *(bf16x8*)&h1l[off] = *(bf16x8*)l8;
    }
}

// ---------------- output: combine GEMM2 halves + b2, relu, @W3 + b3 ; wave per row ----------------
__global__ __launch_bounds__(256) void k_out(const float* __restrict__ P,
                                             const float* __restrict__ b2,
                                             const float* __restrict__ W3,
                                             const float* __restrict__ b3,
                                             float* __restrict__ out) {
    int wid = threadIdx.x >> 6, lane = threadIdx.x & 63;
    int row = blockIdx.x * 4 + wid;
    const float* p0 = P + (size_t)row * HDIM + lane * 8;
    const float* p1 = p0 + PLANE;
    f32x4 a0 = *(const f32x4*)p0, a1 = *(const f32x4*)(p0 + 4);
    f32x4 c0 = *(const f32x4*)p1, c1 = *(const f32x4*)(p1 + 4);
    f32x4 b0 = *(const f32x4*)&b2[lane * 8], b1v = *(const f32x4*)&b2[lane * 8 + 4];
    float h[8];
    #pragma unroll
    for (int i = 0; i < 4; ++i) {
        h[i] = fmaxf(a0[i] + c0[i] + b0[i], 0.f);
        h[4 + i] = fmaxf(a1[i] + c1[i] + b1v[i], 0.f);
    }
    float acc[NOUT];
    #pragma unroll
    for (int n = 0; n < NOUT; ++n) acc[n] = 0.f;
    int k0 = lane * 8;
    #pragma unroll
    for (int i = 0; i < 8; ++i) {
        float hv = h[i];
        const float* w = W3 + (size_t)(k0 + i) * NOUT;
        #pragma unroll
        for (int n = 0; n < NOUT; ++n) acc[n] += hv * w[n];
    }
    #pragma unroll
    for (int off = 32; off >= 1; off >>= 1)
        #pragma unroll
        for (int n = 0; n < NOUT; ++n) acc[n] += __shfl_down(acc[n], off, 64);
    if (lane == 0) {
        #pragma unroll
        for (int n = 0; n < NOUT; ++n) out[(size_t)row * NOUT + n] = acc[n] + b3[n];
    }
}

extern "C" void kernel_launch(void* const* d_in, const int* in_sizes, int n_in,
                              void* d_out, int out_size, void* d_ws, size_t ws_size,
                              hipStream_t stream) {
    const float* beta    = (const float*)d_in[0];
    const float* actions = (const float*)d_in[1];
    const float* power   = (const float*)d_in[2];
    const int*   prev    = (const int*)d_in[3];
    const float* W1      = (const float*)d_in[4];
    const float* b1      = (const float*)d_in[5];
    const float* W2      = (const float*)d_in[6];
    const float* b2      = (const float*)d_in[7];
    const float* W3      = (const float*)d_in[8];
    const float* b3      = (const float*)d_in[9];
    float* out = (float*)d_out;

    char* ws = (char*)d_ws;
    size_t off = 0;
    auto alloc = [&](size_t bytes) { void* p = ws + off; off += (bytes + 255) & ~(size_t)255; return p; };
    float*  total_beta = (float*) alloc((size_t)NROWS * MTASK * 4);
    int*    tasks      = (int*)   alloc((size_t)NROWS * MTOP * 4);
    int*    neighbors  = (int*)   alloc((size_t)NROWS * NNB * 4);
    __bf16* Ah   = (__bf16*)alloc((size_t)NROWS * KP1 * 2);
    __bf16* Al   = (__bf16*)alloc((size_t)NROWS * KP1 * 2);
    __bf16* W1th = (__bf16*)alloc((size_t)HDIM * KP1 * 2);
    __bf16* W2th = (__bf16*)alloc((size_t)HDIM * HDIM * 2);
    __bf16* h1h  = (__bf16*)alloc((size_t)NROWS * HDIM * 2);
    __bf16* h1l  = (__bf16*)alloc((size_t)NROWS * HDIM * 2);
    float*  P    = (float*) alloc(2 * PLANE * 4);

    k_topk<<<NROWS / 4, 256, 0, stream>>>(beta, total_beta, tasks);
    k_nbrs<<<NROWS / 4, 256, 0, stream>>>(total_beta, tasks, neighbors);
    k_build_inputs<<<NROWS / 16, 256, 0, stream>>>(beta, actions, power, prev, tasks,
                                                   neighbors, Ah, Al);
    {
        dim3 gp1(KP1 / 64, HDIM / 64);
        k_prep_wt<<<gp1, 256, 0, stream>>>(W1, W1th, INDIM, HDIM, NKT1);
        dim3 gp2(HDIM / 64, HDIM / 64);
        k_prep_wt<<<gp2, 256, 0, stream>>>(W2, W2th, HDIM, HDIM, NKT2);
    }
    k_gemm_sk<NKT1, NKH1><<<800, 256, 0, stream>>>(Ah, Al, W1th, P);
    k_combine1<<<NROWS / 16, 256, 0, stream>>>(P, b1, h1h, h1l);
    k_gemm_sk<NKT2, NKH2><<<800, 256, 0, stream>>>(h1h, h1l, W2th, P);
    k_out<<<NROWS / 4, 256, 0, stream>>>(P, b2, W3, b3, out);
}

// Round 9
// 217.886 us; speedup vs baseline: 2.6257x; 1.1001x over previous
//
#include <hip/hip_runtime.h>
#include <math.h>

#define NB 8
#define NT 32
#define NAG 50
#define MTASK 100
#define MTOP 10
#define NNB 10
#define LDIM 5
#define HDIM 512
#define INDIM 1610
#define KP1 1664            // INDIM padded to multiple of 64
#define NKT1 (KP1/32)       // 52 k-chunks
#define NKH1 (NKT1/2)       // 26 per split-K half
#define NKT2 (HDIM/32)      // 16
#define NKH2 (NKT2/2)       // 8
#define NROWS (NB*NT*NAG)   // 12800
#define NOUT (MTOP+1)       // 11
#define PLANE ((size_t)NROWS * HDIM)

typedef float f32x4 __attribute__((ext_vector_type(4)));
typedef __bf16 bf16x8 __attribute__((ext_vector_type(8)));

__device__ __forceinline__ void gload16(const __bf16* g, __bf16* l) {
    __builtin_amdgcn_global_load_lds(
        (__attribute__((address_space(1))) void*)(g),
        (__attribute__((address_space(3))) void*)(l), 16, 0, 0);
}

// Tiled operand layout: elem (row, c) of a [rows][KP] matrix lives at
//   (rowblk*NKT*4 + octet)*512 + (row&63)*8 + (c&7),  octet = (c>>5)*4 + ((c>>3)&3)
// One 1KB run holds [octet][64 rows][8 elems] -> one global_load_lds covers it.

// ---------------- top-10 tasks, wave per row ----------------
__global__ __launch_bounds__(256) void k_topk(const float* __restrict__ beta,
                                              float* __restrict__ total_beta,
                                              int* __restrict__ tasks) {
    int wid = threadIdx.x >> 6, lane = threadIdx.x & 63;
    int row = blockIdx.x * 4 + wid;
    const float* bp = beta + (size_t)row * MTASK * LDIM;
    float v1, v2 = -INFINITY;
    {
        const float* p = bp + lane * LDIM;
        v1 = p[0] + p[1] + p[2] + p[3] + p[4];
        total_beta[(size_t)row * MTASK + lane] = v1;
    }
    if (lane + 64 < MTASK) {
        const float* p = bp + (lane + 64) * LDIM;
        v2 = p[0] + p[1] + p[2] + p[3] + p[4];
        total_beta[(size_t)row * MTASK + lane + 64] = v2;
    }
    for (int k = 0; k < MTOP; ++k) {
        float v; int idx;
        if (v1 >= v2) { v = v1; idx = lane; } else { v = v2; idx = lane + 64; }
        #pragma unroll
        for (int m = 1; m < 64; m <<= 1) {
            float vo = __shfl_xor(v, m, 64);
            int io = __shfl_xor(idx, m, 64);
            if (vo > v || (vo == v && io < idx)) { v = vo; idx = io; }
        }
        if (lane == 0) tasks[row * MTOP + k] = idx;
        if (idx == lane) v1 = -INFINITY;
        else if (idx == lane + 64) v2 = -INFINITY;
    }
}

// ---------------- neighbors, wave per row ----------------
__global__ __launch_bounds__(256) void k_nbrs(const float* __restrict__ total_beta,
                                              const int* __restrict__ tasks,
                                              int* __restrict__ neighbors) {
    int wid = threadIdx.x >> 6, lane = threadIdx.x & 63;
    int row = blockIdx.x * 4 + wid;
    int bt = row / NAG, i = row - bt * NAG;
    int tk[MTOP];
    #pragma unroll
    for (int k = 0; k < MTOP; ++k) tk[k] = tasks[row * MTOP + k];
    float v1 = -INFINITY;
    if (lane < NAG) {
        const float* tba = total_beta + ((size_t)bt * NAG + lane) * MTASK;
        float mx = -INFINITY;
        #pragma unroll
        for (int k = 0; k < MTOP; ++k) mx = fmaxf(mx, tba[tk[k]]);
        v1 = (lane == i) ? -INFINITY : mx;
    }
    for (int k = 0; k < NNB; ++k) {
        float v = v1; int idx = lane;
        #pragma unroll
        for (int m = 1; m < 64; m <<= 1) {
            float vo = __shfl_xor(v, m, 64);
            int io = __shfl_xor(idx, m, 64);
            if (vo > v || (vo == v && io < idx)) { v = vo; idx = io; }
        }
        if (lane == 0) neighbors[row * NNB + k] = idx;
        if (idx == lane) v1 = -INFINITY;
    }
}

// ---------------- build inputs v3: LDS-staged gather, 8 rows/block ----------------
__global__ __launch_bounds__(256) void k_build_inputs(
    const float* __restrict__ beta, const float* __restrict__ actions,
    const float* __restrict__ power, const int* __restrict__ prev,
    const int* __restrict__ tasks, const int* __restrict__ neighbors,
    __bf16* __restrict__ Ah, __bf16* __restrict__ Al) {
    int b = blockIdx.x;                 // rows [b*8, b*8+8)
    int t = threadIdx.x;
    __shared__ int tkv[8][MTOP], nbv[8][NNB], pav[8][NNB];
    __shared__ float pwv[8][NNB];
    __shared__ float fbuf[8][500];      // beta features, c-order
    __shared__ float abuf[8][1004];     // action features (padded stride)
    if (t < 80) {
        int lr = t / 10, j = t - lr * 10;
        int row = b * 8 + lr;
        int bt = row / NAG;
        int nbj = neighbors[row * NNB + j];
        nbv[lr][j] = nbj;
        pav[lr][j] = prev[bt * NAG + nbj];
        pwv[lr][j] = power[bt * NAG + nbj];
        tkv[lr][j] = tasks[row * MTOP + j];
    }
    __syncthreads();
    int row0 = b * 8;
    int bt0 = row0 / NAG;               // 8 rows may span two bt only if 50∤... 8|50? no:
    // rows b*8..b*8+7; bt = row/50 can differ within the block. Compute per unit.

    // phase A1: beta pairs. 8 rows x 100 pairs = 800 units.
    #pragma unroll
    for (int it = 0; it < 4; ++it) {
        int idx = t + it * 256;
        if (idx < 800) {
            int l = idx / 100, p = idx - l * 100;
            int k = p / 10, j = p - k * 10;
            int row = row0 + l;
            int bt = row / NAG;
            const float* src = beta + ((size_t)(bt * NAG + nbv[l][j]) * MTASK
                                       + tkv[l][k]) * LDIM;
            int c0 = k * 50 + j * 5;
            #pragma unroll
            for (int i = 0; i < 5; ++i) fbuf[l][c0 + i] = src[i];
        }
    }
    // phase A2: actions. 8 rows x 250 float4 = 2000 units.
    #pragma unroll
    for (int it = 0; it < 8; ++it) {
        int idx = t + it * 256;         // < 2048, guard 2000
        if (idx < 2000) {
            int l = idx / 250, v = idx - l * 250;
            int j = v / 25, q = v - j * 25;
            int row = row0 + l;
            int bt = row / NAG;
            f32x4 a = *(const f32x4*)&actions[(size_t)(bt * NAG + nbv[l][j]) * MTASK + q * 4];
            *(f32x4*)&abuf[l][j * 100 + q * 4] = a;
        }
    }
    __syncthreads();
    // phase B: octet writes from LDS. og = t>>3 (0..31), l = t&7.
    int l = t & 7, og = t >> 3;
    int row = row0 + l;
    int rb = row >> 6, rlo = row & 63;
    #pragma unroll
    for (int s = 0; s < 7; ++s) {
        int o = og + 32 * s;            // 208 octets
        if (o < 208) {
            __bf16 h8[8], l8[8];
            #pragma unroll
            for (int e = 0; e < 8; ++e) {
                int c = o * 8 + e;
                float f;
                if (c < 500) {
                    f = fbuf[l][c];
                } else if (c < 1500) {
                    f = abuf[l][c - 500 + (c - 500) / 100 * 0];  // contiguous j*100+m
                    f = abuf[l][c - 500];
                } else if (c < 1510) {
                    f = pwv[l][c - 1500];
                } else if (c < 1610) {
                    int r2 = c - 1510, k = r2 / NNB, j = r2 - k * NNB;
                    f = (tkv[l][k] == pav[l][j]) ? 1.f : 0.f;
                } else {
                    f = 0.f;
                }
                __bf16 h = (__bf16)f;
                h8[e] = h;
                l8[e] = (__bf16)(f - (float)h);
            }
            size_t off = ((size_t)rb * NKT1 * 4 + o) * 512 + rlo * 8;
            *(bf16x8*)&Ah[off] = *(bf16x8*)h8;
            *(bf16x8*)&Al[off] = *(bf16x8*)l8;
        }
    }
}

// ---------------- weight prep: W[K][N] -> tiled hi-only [N-rows][KP] ----------------
__global__ __launch_bounds__(256) void k_prep_wt(const float* __restrict__ W,
                                                 __bf16* __restrict__ Th,
                                                 int K, int N, int NKT) {
    int kp0 = blockIdx.x * 64, n0 = blockIdx.y * 64;
    __shared__ float lds[64][65];
    int t = threadIdx.x;
    int cc = t & 63, r0 = t >> 6;
    #pragma unroll
    for (int i = 0; i < 16; ++i) {
        int rr = r0 + i * 4;
        int kp = kp0 + rr;
        lds[rr][cc] = (kp < K) ? W[(size_t)kp * N + n0 + cc] : 0.f;
    }
    __syncthreads();
    int nblk = n0 >> 6;
    #pragma unroll
    for (int s = 0; s < 2; ++s) {
        int o = t + s * 256;
        int rn = o & 63, ko = o >> 6;
        int kp = kp0 + ko * 8;
        int kt = kp >> 5, kc = (kp >> 3) & 3;
        __bf16 h8[8];
        #pragma unroll
        for (int e = 0; e < 8; ++e) h8[e] = (__bf16)lds[ko * 8 + e][rn];
        size_t off = ((size_t)(nblk * NKT + kt) * 4 + kc) * 512 + rn * 8;
        *(bf16x8*)&Th[off] = *(bf16x8*)h8;
    }
}

// ---------------- 2-pass chunk-interleaved split-bf16 GEMM, split-K=2 ----------------
template<int NKT, int NKH>
__global__ __launch_bounds__(256, 3) void k_gemm_sk(
    const __bf16* __restrict__ Ahp, const __bf16* __restrict__ Alp,
    const __bf16* __restrict__ Bhp,
    float* __restrict__ P) {
    __shared__ __align__(16) __bf16 sAh[2][4096];
    __shared__ __align__(16) __bf16 sAl[2][4096];
    __shared__ __align__(16) __bf16 sB[2][4096];
    int tid = threadIdx.x, wid = tid >> 6, lane = tid & 63;
    int id = blockIdx.x;
    int swz = (id & 7) * 100 + (id >> 3);       // bijective: 800 % 8 == 0
    int half = swz / 400;
    int rem = swz - half * 400;
    int nt = rem & 3, mt = rem >> 2;
    int koff = half * NKH;

    auto stage = [&](int kk, int buf) {
        #pragma unroll
        for (int j = 0; j < 6; ++j) {
            int seg = wid + 4 * j;              // 0..23
            int grp = seg >> 3;                 // 0:Ah 1:Al 2:Bh
            int s = seg & 7, q = s >> 2, kc = s & 3;
            int ldso = (kc * 128 + q * 64) * 8;
            if (grp == 0) {
                gload16(Ahp + ((size_t)((2 * mt + q) * NKT + kk) * 4 + kc) * 512 + lane * 8,
                        &sAh[buf][ldso]);
            } else if (grp == 1) {
                gload16(Alp + ((size_t)((2 * mt + q) * NKT + kk) * 4 + kc) * 512 + lane * 8,
                        &sAl[buf][ldso]);
            } else {
                gload16(Bhp + ((size_t)((2 * nt + q) * NKT + kk) * 4 + kc) * 512 + lane * 8,
                        &sB[buf][ldso]);
            }
        }
    };

    int wr = wid >> 1, wc = wid & 1;
    int lrow = lane & 15, lk = lane >> 4;
    int aoff = (lk * 128 + wr * 64 + lrow) * 8;
    int boff = (lk * 128 + wc * 64 + lrow) * 8;
    f32x4 acc[4][4] = {};

    stage(koff, 0);
    for (int kt = 0; kt < NKH; ++kt) {
        int buf = kt & 1;
        __syncthreads();
        if (kt + 1 < NKH) stage(koff + kt + 1, buf ^ 1);
        bf16x8 ah[4], al[4], bh[4];
        #pragma unroll
        for (int i = 0; i < 4; ++i) {
            ah[i] = *(const bf16x8*)&sAh[buf][aoff + i * 128];
            al[i] = *(const bf16x8*)&sAl[buf][aoff + i * 128];
        }
        #pragma unroll
        for (int j = 0; j < 4; ++j) bh[j] = *(const bf16x8*)&sB[buf][boff + j * 128];
        #pragma unroll
        for (int i = 0; i < 4; ++i)
            #pragma unroll
            for (int j = 0; j < 4; ++j) {
                acc[i][j] = __builtin_amdgcn_mfma_f32_16x16x32_bf16(ah[i], bh[j], acc[i][j], 0, 0, 0);
                acc[i][j] = __builtin_amdgcn_mfma_f32_16x16x32_bf16(al[i], bh[j], acc[i][j], 0, 0, 0);
            }
    }

    float* pout = P + (size_t)half * PLANE;
    #pragma unroll
    for (int i = 0; i < 4; ++i) {
        int mrow = mt * 128 + wr * 64 + i * 16 + lk * 4;
        #pragma unroll
        for (int j = 0; j < 4; ++j) {
            int n = nt * 128 + wc * 64 + j * 16 + lrow;
            #pragma unroll
            for (int r = 0; r < 4; ++r)
                pout[(size_t)(mrow + r) * HDIM + n] = acc[i][j][r];
        }
    }
}

// ---------------- combine1: coalesced reads, LDS transpose, coalesced tiled writes ----------------
__global__ __launch_bounds__(256) void k_combine1(const float* __restrict__ P,
                                                  const float* __restrict__ b1,
                                                  __bf16* __restrict__ h1h,
                                                  __bf16* __restrict__ h1l) {
    int b = blockIdx.x;                  // rows [b*16, b*16+16)
    int t = threadIdx.x;
    __shared__ float lds[16][523];
    int rb = b >> 2, q = b & 3;
    #pragma unroll
    for (int rep = 0; rep < 8; ++rep) {
        int g = rep * 1024 + t * 4;
        int lr = g >> 9, col = g & 511;
        size_t base = (size_t)(b * 16 + lr) * HDIM + col;
        f32x4 a = *(const f32x4*)&P[base];
        f32x4 c = *(const f32x4*)&P[PLANE + base];
        f32x4 bv = *(const f32x4*)&b1[col];
        #pragma unroll
        for (int i = 0; i < 4; ++i)
            lds[lr][col + i] = fmaxf(a[i] + c[i] + bv[i], 0.f);
    }
    __syncthreads();
    int l = t & 15, og = t >> 4;
    #pragma unroll
    for (int s = 0; s < 4; ++s) {
        int o = og + 16 * s;
        __bf16 h8[8], l8[8];
        #pragma unroll
        for (int e = 0; e < 8; ++e) {
            float f = lds[l][o * 8 + e];
            __bf16 h = (__bf16)f;
            h8[e] = h;
            l8[e] = (__bf16)(f - (float)h);
        }
        size_t off = ((size_t)rb * 64 + o) * 512 + (q * 16 + l) * 8;
        *(bf16x8*)&h1h[off] = *(bf16x8*)h8;
        *(bf16x8*)&h1l[off] = *(bf16x8*)l8;
    }
}

// ---------------- output: combine GEMM2 halves + b2, relu, @W3 + b3 ; wave per row ----------------
__global__ __launch_bounds__(256) void k_out(const float* __restrict__ P,
                                             const float* __restrict__ b2,
                                             const float* __restrict__ W3,
                                             const float* __restrict__ b3,
                                             float* __restrict__ out) {
    int wid = threadIdx.x >> 6, lane = threadIdx.x & 63;
    int row = blockIdx.x * 4 + wid;
    const float* p0 = P + (size_t)row * HDIM + lane * 8;
    const float* p1 = p0 + PLANE;
    f32x4 a0 = *(const f32x4*)p0, a1 = *(const f32x4*)(p0 + 4);
    f32x4 c0 = *(const f32x4*)p1, c1 = *(const f32x4*)(p1 + 4);
    f32x4 b0 = *(const f32x4*)&b2[lane * 8], b1v = *(const f32x4*)&b2[lane * 8 + 4];
    float h[8];
    #pragma unroll
    for (int i = 0; i < 4; ++i) {
        h[i] = fmaxf(a0[i] + c0[i] + b0[i], 0.f);
        h[4 + i] = fmaxf(a1[i] + c1[i] + b1v[i], 0.f);
    }
    float acc[NOUT];
    #pragma unroll
    for (int n = 0; n < NOUT; ++n) acc[n] = 0.f;
    int k0 = lane * 8;
    #pragma unroll
    for (int i = 0; i < 8; ++i) {
        float hv = h[i];
        const float* w = W3 + (size_t)(k0 + i) * NOUT;
        #pragma unroll
        for (int n = 0; n < NOUT; ++n) acc[n] += hv * w[n];
    }
    #pragma unroll
    for (int off = 32; off >= 1; off >>= 1)
        #pragma unroll
        for (int n = 0; n < NOUT; ++n) acc[n] += __shfl_down(acc[n], off, 64);
    if (lane == 0) {
        #pragma unroll
        for (int n = 0; n < NOUT; ++n) out[(size_t)row * NOUT + n] = acc[n] + b3[n];
    }
}

extern "C" void kernel_launch(void* const* d_in, const int* in_sizes, int n_in,
                              void* d_out, int out_size, void* d_ws, size_t ws_size,
                              hipStream_t stream) {
    const float* beta    = (const float*)d_in[0];
    const float* actions = (const float*)d_in[1];
    const float* power   = (const float*)d_in[2];
    const int*   prev    = (const int*)d_in[3];
    const float* W1      = (const float*)d_in[4];
    const float* b1      = (const float*)d_in[5];
    const float* W2      = (const float*)d_in[6];
    const float* b2      = (const float*)d_in[7];
    const float* W3      = (const float*)d_in[8];
    const float* b3      = (const float*)d_in[9];
    float* out = (float*)d_out;

    char* ws = (char*)d_ws;
    size_t off = 0;
    auto alloc = [&](size_t bytes) { void* p = ws + off; off += (bytes + 255) & ~(size_t)255; return p; };
    float*  total_beta = (float*) alloc((size_t)NROWS * MTASK * 4);
    int*    tasks      = (int*)   alloc((size_t)NROWS * MTOP * 4);
    int*    neighbors  = (int*)   alloc((size_t)NROWS * NNB * 4);
    __bf16* Ah   = (__bf16*)alloc((size_t)NROWS * KP1 * 2);
    __bf16* Al   = (__bf16*)alloc((size_t)NROWS * KP1 * 2);
    __bf16* W1th = (__bf16*)alloc((size_t)HDIM * KP1 * 2);
    __bf16* W2th = (__bf16*)alloc((size_t)HDIM * HDIM * 2);
    __bf16* h1h  = (__bf16*)alloc((size_t)NROWS * HDIM * 2);
    __bf16* h1l  = (__bf16*)alloc((size_t)NROWS * HDIM * 2);
    float*  P    = (float*) alloc(2 * PLANE * 4);

    k_topk<<<NROWS / 4, 256, 0, stream>>>(beta, total_beta, tasks);
    k_nbrs<<<NROWS / 4, 256, 0, stream>>>(total_beta, tasks, neighbors);
    k_build_inputs<<<NROWS / 8, 256, 0, stream>>>(beta, actions, power, prev, tasks,
                                                  neighbors, Ah, Al);
    {
        dim3 gp1(KP1 / 64, HDIM / 64);
        k_prep_wt<<<gp1, 256, 0, stream>>>(W1, W1th, INDIM, HDIM, NKT1);
        dim3 gp2(HDIM / 64, HDIM / 64);
        k_prep_wt<<<gp2, 256, 0, stream>>>(W2, W2th, HDIM, HDIM, NKT2);
    }
    k_gemm_sk<NKT1, NKH1><<<800, 256, 0, stream>>>(Ah, Al, W1th, P);
    k_combine1<<<NROWS / 16, 256, 0, stream>>>(P, b1, h1h, h1l);
    k_gemm_sk<NKT2, NKH2><<<800, 256, 0, stream>>>(h1h, h1l, W2th, P);
    k_out<<<NROWS / 4, 256, 0, stream>>>(P, b2, W3, b3, out);
}

// Round 10
// 197.847 us; speedup vs baseline: 2.8917x; 1.1013x over previous
//
#include <hip/hip_runtime.h>
#include <math.h>

#define NB 8
#define NT 32
#define NAG 50
#define MTASK 100
#define MTOP 10
#define NNB 10
#define LDIM 5
#define HDIM 512
#define INDIM 1610
#define KP1 1664            // INDIM padded to multiple of 64
#define NKT1 (KP1/32)       // 52 k-chunks
#define NKH1 (NKT1/2)       // 26 per split-K half
#define NKT2 (HDIM/32)      // 16
#define NROWS (NB*NT*NAG)   // 12800
#define NOUT (MTOP+1)       // 11
#define PLANE ((size_t)NROWS * HDIM)

typedef float f32x4 __attribute__((ext_vector_type(4)));
typedef __bf16 bf16x8 __attribute__((ext_vector_type(8)));

__device__ __forceinline__ void gload16(const __bf16* g, __bf16* l) {
    __builtin_amdgcn_global_load_lds(
        (__attribute__((address_space(1))) void*)(g),
        (__attribute__((address_space(3))) void*)(l), 16, 0, 0);
}

// Tiled operand layout: elem (row, c) of a [rows][KP] matrix lives at
//   (rowblk*NKT*4 + octet)*512 + (row&63)*8 + (c&7),  octet = (c>>5)*4 + ((c>>3)&3)
// One 1KB run holds [octet][64 rows][8 elems] -> one global_load_lds covers it.

// ---------------- top-10 tasks, wave per row ----------------
__global__ __launch_bounds__(256) void k_topk(const float* __restrict__ beta,
                                              float* __restrict__ total_beta,
                                              int* __restrict__ tasks) {
    int wid = threadIdx.x >> 6, lane = threadIdx.x & 63;
    int row = blockIdx.x * 4 + wid;
    const float* bp = beta + (size_t)row * MTASK * LDIM;
    float v1, v2 = -INFINITY;
    {
        const float* p = bp + lane * LDIM;
        v1 = p[0] + p[1] + p[2] + p[3] + p[4];
        total_beta[(size_t)row * MTASK + lane] = v1;
    }
    if (lane + 64 < MTASK) {
        const float* p = bp + (lane + 64) * LDIM;
        v2 = p[0] + p[1] + p[2] + p[3] + p[4];
        total_beta[(size_t)row * MTASK + lane + 64] = v2;
    }
    for (int k = 0; k < MTOP; ++k) {
        float v; int idx;
        if (v1 >= v2) { v = v1; idx = lane; } else { v = v2; idx = lane + 64; }
        #pragma unroll
        for (int m = 1; m < 64; m <<= 1) {
            float vo = __shfl_xor(v, m, 64);
            int io = __shfl_xor(idx, m, 64);
            if (vo > v || (vo == v && io < idx)) { v = vo; idx = io; }
        }
        if (lane == 0) tasks[row * MTOP + k] = idx;
        if (idx == lane) v1 = -INFINITY;
        else if (idx == lane + 64) v2 = -INFINITY;
    }
}

// ---------------- neighbors, wave per row ----------------
__global__ __launch_bounds__(256) void k_nbrs(const float* __restrict__ total_beta,
                                              const int* __restrict__ tasks,
                                              int* __restrict__ neighbors) {
    int wid = threadIdx.x >> 6, lane = threadIdx.x & 63;
    int row = blockIdx.x * 4 + wid;
    int bt = row / NAG, i = row - bt * NAG;
    int tk[MTOP];
    #pragma unroll
    for (int k = 0; k < MTOP; ++k) tk[k] = tasks[row * MTOP + k];
    float v1 = -INFINITY;
    if (lane < NAG) {
        const float* tba = total_beta + ((size_t)bt * NAG + lane) * MTASK;
        float mx = -INFINITY;
        #pragma unroll
        for (int k = 0; k < MTOP; ++k) mx = fmaxf(mx, tba[tk[k]]);
        v1 = (lane == i) ? -INFINITY : mx;
    }
    for (int k = 0; k < NNB; ++k) {
        float v = v1; int idx = lane;
        #pragma unroll
        for (int m = 1; m < 64; m <<= 1) {
            float vo = __shfl_xor(v, m, 64);
            int io = __shfl_xor(idx, m, 64);
            if (vo > v || (vo == v && io < idx)) { v = vo; idx = io; }
        }
        if (lane == 0) neighbors[row * NNB + k] = idx;
        if (idx == lane) v1 = -INFINITY;
    }
}

// ---------------- build inputs: LDS-staged gather, 8 rows/block ----------------
__global__ __launch_bounds__(256) void k_build_inputs(
    const float* __restrict__ beta, const float* __restrict__ actions,
    const float* __restrict__ power, const int* __restrict__ prev,
    const int* __restrict__ tasks, const int* __restrict__ neighbors,
    __bf16* __restrict__ Ah, __bf16* __restrict__ Al) {
    int b = blockIdx.x;                 // rows [b*8, b*8+8)
    int t = threadIdx.x;
    __shared__ int tkv[8][MTOP], nbv[8][NNB], pav[8][NNB];
    __shared__ float pwv[8][NNB];
    __shared__ float fbuf[8][500];
    __shared__ float abuf[8][1004];
    if (t < 80) {
        int lr = t / 10, j = t - lr * 10;
        int row = b * 8 + lr;
        int bt = row / NAG;
        int nbj = neighbors[row * NNB + j];
        nbv[lr][j] = nbj;
        pav[lr][j] = prev[bt * NAG + nbj];
        pwv[lr][j] = power[bt * NAG + nbj];
        tkv[lr][j] = tasks[row * MTOP + j];
    }
    __syncthreads();
    int row0 = b * 8;
    #pragma unroll
    for (int it = 0; it < 4; ++it) {
        int idx = t + it * 256;
        if (idx < 800) {
            int l = idx / 100, p = idx - l * 100;
            int k = p / 10, j = p - k * 10;
            int row = row0 + l;
            int bt = row / NAG;
            const float* src = beta + ((size_t)(bt * NAG + nbv[l][j]) * MTASK
                                       + tkv[l][k]) * LDIM;
            int c0 = k * 50 + j * 5;
            #pragma unroll
            for (int i = 0; i < 5; ++i) fbuf[l][c0 + i] = src[i];
        }
    }
    #pragma unroll
    for (int it = 0; it < 8; ++it) {
        int idx = t + it * 256;
        if (idx < 2000) {
            int l = idx / 250, v = idx - l * 250;
            int j = v / 25, q = v - j * 25;
            int row = row0 + l;
            int bt = row / NAG;
            f32x4 a = *(const f32x4*)&actions[(size_t)(bt * NAG + nbv[l][j]) * MTASK + q * 4];
            *(f32x4*)&abuf[l][j * 100 + q * 4] = a;
        }
    }
    __syncthreads();
    int l = t & 7, og = t >> 3;
    int row = row0 + l;
    int rb = row >> 6, rlo = row & 63;
    #pragma unroll
    for (int s = 0; s < 7; ++s) {
        int o = og + 32 * s;
        if (o < 208) {
            __bf16 h8[8], l8[8];
            #pragma unroll
            for (int e = 0; e < 8; ++e) {
                int c = o * 8 + e;
                float f;
                if (c < 500) {
                    f = fbuf[l][c];
                } else if (c < 1500) {
                    f = abuf[l][c - 500];
                } else if (c < 1510) {
                    f = pwv[l][c - 1500];
                } else if (c < 1610) {
                    int r2 = c - 1510, k = r2 / NNB, j = r2 - k * NNB;
                    f = (tkv[l][k] == pav[l][j]) ? 1.f : 0.f;
                } else {
                    f = 0.f;
                }
                __bf16 h = (__bf16)f;
                h8[e] = h;
                l8[e] = (__bf16)(f - (float)h);
            }
            size_t off = ((size_t)rb * NKT1 * 4 + o) * 512 + rlo * 8;
            *(bf16x8*)&Ah[off] = *(bf16x8*)h8;
            *(bf16x8*)&Al[off] = *(bf16x8*)l8;
        }
    }
}

// ---------------- merged weight prep: W1 and W2 -> tiled hi-only ----------------
__global__ __launch_bounds__(256) void k_prep_wt(const float* __restrict__ W1,
                                                 const float* __restrict__ W2,
                                                 __bf16* __restrict__ T1,
                                                 __bf16* __restrict__ T2) {
    int bx = blockIdx.x, n0 = blockIdx.y * 64;
    const float* W; __bf16* T; int K, NKT, kp0;
    if (bx < KP1 / 64) { W = W1; T = T1; K = INDIM; NKT = NKT1; kp0 = bx * 64; }
    else               { W = W2; T = T2; K = HDIM;  NKT = NKT2; kp0 = (bx - KP1 / 64) * 64; }
    __shared__ float lds[64][65];
    int t = threadIdx.x;
    int cc = t & 63, r0 = t >> 6;
    #pragma unroll
    for (int i = 0; i < 16; ++i) {
        int rr = r0 + i * 4;
        int kp = kp0 + rr;
        lds[rr][cc] = (kp < K) ? W[(size_t)kp * HDIM + n0 + cc] : 0.f;
    }
    __syncthreads();
    int nblk = n0 >> 6;
    #pragma unroll
    for (int s = 0; s < 2; ++s) {
        int o = t + s * 256;
        int rn = o & 63, ko = o >> 6;
        int kp = kp0 + ko * 8;
        int kt = kp >> 5, kc = (kp >> 3) & 3;
        __bf16 h8[8];
        #pragma unroll
        for (int e = 0; e < 8; ++e) h8[e] = (__bf16)lds[ko * 8 + e][rn];
        size_t off = ((size_t)(nblk * NKT + kt) * 4 + kc) * 512 + rn * 8;
        *(bf16x8*)&T[off] = *(bf16x8*)h8;
    }
}

// ---------------- 2-pass split-bf16 GEMM, 64x128 tile, A-lo via register loads ----
// LDS stages only {Ah, Bh} (24 KB dbuf). Al frags load global->VGPR per wave with
// the SAME (lane,e)->k map as the LDS path (k-permutation cancels in MFMA).
// Grid: 800*HALVES blocks, XCD-bijective swizzle (grid % 8 == 0).
template<int NKT, int NKH, int CPX, bool RELU>
__global__ __launch_bounds__(256, 2) void k_gemm_sk(
    const __bf16* __restrict__ Ahp, const __bf16* __restrict__ Alp,
    const __bf16* __restrict__ Bhp, const float* __restrict__ bias,
    float* __restrict__ P) {
    __shared__ __align__(16) __bf16 sAh[2][2048];   // [kc(4)][64 rows][8]
    __shared__ __align__(16) __bf16 sB[2][4096];    // [kc(4)][128 cols][8]
    int tid = threadIdx.x, wid = tid >> 6, lane = tid & 63;
    int id = blockIdx.x;
    int swz = (id & 7) * CPX + (id >> 3);
    int half = swz / 800;                 // 0 when grid <= 800
    int rem = swz - half * 800;
    int nt = rem & 3, mt = rem >> 2;      // mt in [0,200)
    int koff = half * NKH;

    auto stage = [&](int kk, int buf) {
        #pragma unroll
        for (int j = 0; j < 3; ++j) {
            int seg = wid + 4 * j;        // 0..11
            if (seg < 4) {
                gload16(Ahp + ((size_t)(mt * NKT + kk) * 4 + seg) * 512 + lane * 8,
                        &sAh[buf][seg * 512]);
            } else {
                int s = seg - 4, q = s >> 2, kc = s & 3;
                gload16(Bhp + ((size_t)((2 * nt + q) * NKT + kk) * 4 + kc) * 512 + lane * 8,
                        &sB[buf][(kc * 128 + q * 64) * 8]);
            }
        }
    };

    int wr = wid >> 1, wc = wid & 1;      // 2x2 waves over 64x128
    int lrow = lane & 15, lk = lane >> 4;
    f32x4 acc[2][4] = {};

    stage(koff, 0);
    for (int kt = 0; kt < NKH; ++kt) {
        int buf = kt & 1;
        int kk = koff + kt;
        __syncthreads();
        // A-lo register loads FIRST (oldest vmcnt entries -> counted wait, not drain)
        size_t abase = ((size_t)(mt * NKT + kk) * 4 + lk) * 512 + (wr * 32 + lrow) * 8;
        bf16x8 al0 = *(const bf16x8*)(Alp + abase);
        bf16x8 al1 = *(const bf16x8*)(Alp + abase + 128);   // +16 rows
        if (kt + 1 < NKH) stage(kk + 1, buf ^ 1);
        bf16x8 ah[2], bh[4];
        #pragma unroll
        for (int i = 0; i < 2; ++i)
            ah[i] = *(const bf16x8*)&sAh[buf][(lk * 64 + wr * 32 + i * 16 + lrow) * 8];
        #pragma unroll
        for (int j = 0; j < 4; ++j)
            bh[j] = *(const bf16x8*)&sB[buf][(lk * 128 + wc * 64 + j * 16 + lrow) * 8];
        #pragma unroll
        for (int i = 0; i < 2; ++i)
            #pragma unroll
            for (int j = 0; j < 4; ++j)
                acc[i][j] = __builtin_amdgcn_mfma_f32_16x16x32_bf16(ah[i], bh[j], acc[i][j], 0, 0, 0);
        #pragma unroll
        for (int j = 0; j < 4; ++j) {
            acc[0][j] = __builtin_amdgcn_mfma_f32_16x16x32_bf16(al0, bh[j], acc[0][j], 0, 0, 0);
            acc[1][j] = __builtin_amdgcn_mfma_f32_16x16x32_bf16(al1, bh[j], acc[1][j], 0, 0, 0);
        }
    }

    float* pout = P + (size_t)half * PLANE;
    #pragma unroll
    for (int i = 0; i < 2; ++i) {
        int mrow = mt * 64 + wr * 32 + i * 16 + lk * 4;
        #pragma unroll
        for (int j = 0; j < 4; ++j) {
            int n = nt * 128 + wc * 64 + j * 16 + lrow;
            float bv = RELU ? bias[n] : 0.f;
            #pragma unroll
            for (int r = 0; r < 4; ++r) {
                float c = acc[i][j][r] + bv;
                if (RELU) c = fmaxf(c, 0.f);
                pout[(size_t)(mrow + r) * HDIM + n] = c;
            }
        }
    }
}

// ---------------- combine1: GEMM1 halves + b1 -> relu -> split bf16 tiled ----------------
__global__ __launch_bounds__(256) void k_combine1(const float* __restrict__ P,
                                                  const float* __restrict__ b1,
                                                  __bf16* __restrict__ h1h,
                                                  __bf16* __restrict__ h1l) {
    int b = blockIdx.x;                  // rows [b*16, b*16+16)
    int t = threadIdx.x;
    __shared__ float lds[16][523];
    int rb = b >> 2, q = b & 3;
    #pragma unroll
    for (int rep = 0; rep < 8; ++rep) {
        int g = rep * 1024 + t * 4;
        int lr = g >> 9, col = g & 511;
        size_t base = (size_t)(b * 16 + lr) * HDIM + col;
        f32x4 a = *(const f32x4*)&P[base];
        f32x4 c = *(const f32x4*)&P[PLANE + base];
        f32x4 bv = *(const f32x4*)&b1[col];
        #pragma unroll
        for (int i = 0; i < 4; ++i)
            lds[lr][col + i] = fmaxf(a[i] + c[i] + bv[i], 0.f);
    }
    __syncthreads();
    int l = t & 15, og = t >> 4;
    #pragma unroll
    for (int s = 0; s < 4; ++s) {
        int o = og + 16 * s;
        __bf16 h8[8], l8[8];
        #pragma unroll
        for (int e = 0; e < 8; ++e) {
            float f = lds[l][o * 8 + e];
            __bf16 h = (__bf16)f;
            h8[e] = h;
            l8[e] = (__bf16)(f - (float)h);
        }
        size_t off = ((size_t)rb * 64 + o) * 512 + (q * 16 + l) * 8;
        *(bf16x8*)&h1h[off] = *(bf16x8*)h8;
        *(bf16x8*)&h1l[off] = *(bf16x8*)l8;
    }
}

// ---------------- output: h2act @ W3 + b3 ; wave per row ----------------
__global__ __launch_bounds__(256) void k_out(const float* __restrict__ h2,
                                             const float* __restrict__ W3,
                                             const float* __restrict__ b3,
                                             float* __restrict__ out) {
    int wid = threadIdx.x >> 6, lane = threadIdx.x & 63;
    int row = blockIdx.x * 4 + wid;
    const float* hp = h2 + (size_t)row * HDIM + lane * 8;
    f32x4 a0 = *(const f32x4*)hp;
    f32x4 a1 = *(const f32x4*)(hp + 4);
    float h[8];
    #pragma unroll
    for (int i = 0; i < 4; ++i) { h[i] = a0[i]; h[4 + i] = a1[i]; }
    float acc[NOUT];
    #pragma unroll
    for (int n = 0; n < NOUT; ++n) acc[n] = 0.f;
    int k0 = lane * 8;
    #pragma unroll
    for (int i = 0; i < 8; ++i) {
        float hv = h[i];
        const float* w = W3 + (size_t)(k0 + i) * NOUT;
        #pragma unroll
        for (int n = 0; n < NOUT; ++n) acc[n] += hv * w[n];
    }
    #pragma unroll
    for (int off = 32; off >= 1; off >>= 1)
        #pragma unroll
        for (int n = 0; n < NOUT; ++n) acc[n] += __shfl_down(acc[n], off, 64);
    if (lane == 0) {
        #pragma unroll
        for (int n = 0; n < NOUT; ++n) out[(size_t)row * NOUT + n] = acc[n] + b3[n];
    }
}

extern "C" void kernel_launch(void* const* d_in, const int* in_sizes, int n_in,
                              void* d_out, int out_size, void* d_ws, size_t ws_size,
                              hipStream_t stream) {
    const float* beta    = (const float*)d_in[0];
    const float* actions = (const float*)d_in[1];
    const float* power   = (const float*)d_in[2];
    const int*   prev    = (const int*)d_in[3];
    const float* W1      = (const float*)d_in[4];
    const float* b1      = (const float*)d_in[5];
    const float* W2      = (const float*)d_in[6];
    const float* b2      = (const float*)d_in[7];
    const float* W3      = (const float*)d_in[8];
    const float* b3      = (const float*)d_in[9];
    float* out = (float*)d_out;

    char* ws = (char*)d_ws;
    size_t off = 0;
    auto alloc = [&](size_t bytes) { void* p = ws + off; off += (bytes + 255) & ~(size_t)255; return p; };
    float*  total_beta = (float*) alloc((size_t)NROWS * MTASK * 4);
    int*    tasks      = (int*)   alloc((size_t)NROWS * MTOP * 4);
    int*    neighbors  = (int*)   alloc((size_t)NROWS * NNB * 4);
    __bf16* Ah   = (__bf16*)alloc((size_t)NROWS * KP1 * 2);
    __bf16* Al   = (__bf16*)alloc((size_t)NROWS * KP1 * 2);
    __bf16* W1th = (__bf16*)alloc((size_t)HDIM * KP1 * 2);
    __bf16* W2th = (__bf16*)alloc((size_t)HDIM * HDIM * 2);
    __bf16* h1h  = (__bf16*)alloc((size_t)NROWS * HDIM * 2);
    __bf16* h1l  = (__bf16*)alloc((size_t)NROWS * HDIM * 2);
    float*  P    = (float*) alloc(2 * PLANE * 4);   // GEMM1 halves; plane0 reused as h2act

    k_topk<<<NROWS / 4, 256, 0, stream>>>(beta, total_beta, tasks);
    k_nbrs<<<NROWS / 4, 256, 0, stream>>>(total_beta, tasks, neighbors);
    k_build_inputs<<<NROWS / 8, 256, 0, stream>>>(beta, actions, power, prev, tasks,
                                                  neighbors, Ah, Al);
    {
        dim3 gp(KP1 / 64 + HDIM / 64, HDIM / 64);
        k_prep_wt<<<gp, 256, 0, stream>>>(W1, W2, W1th, W2th);
    }
    // GEMM1: split-K=2, grid 1600 (200 mt x 4 nt x 2 halves)
    k_gemm_sk<NKT1, NKH1, 200, false><<<1600, 256, 0, stream>>>(Ah, Al, W1th, nullptr, P);
    k_combine1<<<NROWS / 16, 256, 0, stream>>>(P, b1, h1h, h1l);
    // GEMM2: no split-K, grid 800; epilogue = +b2, relu -> h2act (P plane 0)
    k_gemm_sk<NKT2, NKT2, 100, true><<<800, 256, 0, stream>>>(h1h, h1l, W2th, b2, P);
    k_out<<<NROWS / 4, 256, 0, stream>>>(P, W3, b3, out);
}

// Round 11
// 191.189 us; speedup vs baseline: 2.9924x; 1.0348x over previous
//
#include <hip/hip_runtime.h>
#include <math.h>

#define NB 8
#define NT 32
#define NAG 50
#define MTASK 100
#define MTOP 10
#define NNB 10
#define LDIM 5
#define HDIM 512
#define INDIM 1610
#define KP1 1664            // INDIM padded to multiple of 64
#define NKT1 (KP1/32)       // 52 k-chunks
#define NKT2 (HDIM/32)      // 16
#define NROWS (NB*NT*NAG)   // 12800
#define NOUT (MTOP+1)       // 11
#define PLANE ((size_t)NROWS * HDIM)

typedef float f32x4 __attribute__((ext_vector_type(4)));
typedef __bf16 bf16x8 __attribute__((ext_vector_type(8)));

__device__ __forceinline__ void gload16(const __bf16* g, __bf16* l) {
    __builtin_amdgcn_global_load_lds(
        (__attribute__((address_space(1))) void*)(g),
        (__attribute__((address_space(3))) void*)(l), 16, 0, 0);
}

// A-side tiled layout (32-row blocks): elem (row, c) lives at
//   (rowblk32 * NKT*4 + octet)*256 + (row&31)*8 + (c&7),  octet = c>>3 (kt*4+kc)
// -> one 512B run per octet; one gload16 (1KB) covers two consecutive octets.
// B-side tiled layout (64-col blocks): (colblk64 * NKT*4 + octet)*512 + (col&63)*8 + e.

// ---------------- top-10 tasks, wave per row ----------------
__global__ __launch_bounds__(256) void k_topk(const float* __restrict__ beta,
                                              float* __restrict__ total_beta,
                                              int* __restrict__ tasks) {
    int wid = threadIdx.x >> 6, lane = threadIdx.x & 63;
    int row = blockIdx.x * 4 + wid;
    const float* bp = beta + (size_t)row * MTASK * LDIM;
    float v1, v2 = -INFINITY;
    {
        const float* p = bp + lane * LDIM;
        v1 = p[0] + p[1] + p[2] + p[3] + p[4];
        total_beta[(size_t)row * MTASK + lane] = v1;
    }
    if (lane + 64 < MTASK) {
        const float* p = bp + (lane + 64) * LDIM;
        v2 = p[0] + p[1] + p[2] + p[3] + p[4];
        total_beta[(size_t)row * MTASK + lane + 64] = v2;
    }
    for (int k = 0; k < MTOP; ++k) {
        float v; int idx;
        if (v1 >= v2) { v = v1; idx = lane; } else { v = v2; idx = lane + 64; }
        #pragma unroll
        for (int m = 1; m < 64; m <<= 1) {
            float vo = __shfl_xor(v, m, 64);
            int io = __shfl_xor(idx, m, 64);
            if (vo > v || (vo == v && io < idx)) { v = vo; idx = io; }
        }
        if (lane == 0) tasks[row * MTOP + k] = idx;
        if (idx == lane) v1 = -INFINITY;
        else if (idx == lane + 64) v2 = -INFINITY;
    }
}

// ---------------- neighbors, wave per row ----------------
__global__ __launch_bounds__(256) void k_nbrs(const float* __restrict__ total_beta,
                                              const int* __restrict__ tasks,
                                              int* __restrict__ neighbors) {
    int wid = threadIdx.x >> 6, lane = threadIdx.x & 63;
    int row = blockIdx.x * 4 + wid;
    int bt = row / NAG, i = row - bt * NAG;
    int tk[MTOP];
    #pragma unroll
    for (int k = 0; k < MTOP; ++k) tk[k] = tasks[row * MTOP + k];
    float v1 = -INFINITY;
    if (lane < NAG) {
        const float* tba = total_beta + ((size_t)bt * NAG + lane) * MTASK;
        float mx = -INFINITY;
        #pragma unroll
        for (int k = 0; k < MTOP; ++k) mx = fmaxf(mx, tba[tk[k]]);
        v1 = (lane == i) ? -INFINITY : mx;
    }
    for (int k = 0; k < NNB; ++k) {
        float v = v1; int idx = lane;
        #pragma unroll
        for (int m = 1; m < 64; m <<= 1) {
            float vo = __shfl_xor(v, m, 64);
            int io = __shfl_xor(idx, m, 64);
            if (vo > v || (vo == v && io < idx)) { v = vo; idx = io; }
        }
        if (lane == 0) neighbors[row * NNB + k] = idx;
        if (idx == lane) v1 = -INFINITY;
    }
}

// ---------------- build inputs: LDS-staged gather, 8 rows/block, 32-row-block tiled out ----
__global__ __launch_bounds__(256) void k_build_inputs(
    const float* __restrict__ beta, const float* __restrict__ actions,
    const float* __restrict__ power, const int* __restrict__ prev,
    const int* __restrict__ tasks, const int* __restrict__ neighbors,
    __bf16* __restrict__ Ah, __bf16* __restrict__ Al) {
    int b = blockIdx.x;                 // rows [b*8, b*8+8)
    int t = threadIdx.x;
    __shared__ int tkv[8][MTOP], nbv[8][NNB], pav[8][NNB];
    __shared__ float pwv[8][NNB];
    __shared__ float fbuf[8][500];
    __shared__ float abuf[8][1004];
    if (t < 80) {
        int lr = t / 10, j = t - lr * 10;
        int row = b * 8 + lr;
        int bt = row / NAG;
        int nbj = neighbors[row * NNB + j];
        nbv[lr][j] = nbj;
        pav[lr][j] = prev[bt * NAG + nbj];
        pwv[lr][j] = power[bt * NAG + nbj];
        tkv[lr][j] = tasks[row * MTOP + j];
    }
    __syncthreads();
    int row0 = b * 8;
    #pragma unroll
    for (int it = 0; it < 4; ++it) {
        int idx = t + it * 256;
        if (idx < 800) {
            int l = idx / 100, p = idx - l * 100;
            int k = p / 10, j = p - k * 10;
            int row = row0 + l;
            int bt = row / NAG;
            const float* src = beta + ((size_t)(bt * NAG + nbv[l][j]) * MTASK
                                       + tkv[l][k]) * LDIM;
            int c0 = k * 50 + j * 5;
            #pragma unroll
            for (int i = 0; i < 5; ++i) fbuf[l][c0 + i] = src[i];
        }
    }
    #pragma unroll
    for (int it = 0; it < 8; ++it) {
        int idx = t + it * 256;
        if (idx < 2000) {
            int l = idx / 250, v = idx - l * 250;
            int j = v / 25, q = v - j * 25;
            int row = row0 + l;
            int bt = row / NAG;
            f32x4 a = *(const f32x4*)&actions[(size_t)(bt * NAG + nbv[l][j]) * MTASK + q * 4];
            *(f32x4*)&abuf[l][j * 100 + q * 4] = a;
        }
    }
    __syncthreads();
    int l = t & 7, og = t >> 3;
    int row = row0 + l;
    int rb = row >> 5, rlo = row & 31;
    #pragma unroll
    for (int s = 0; s < 7; ++s) {
        int o = og + 32 * s;
        if (o < 208) {                  // NKT1*4
            __bf16 h8[8], l8[8];
            #pragma unroll
            for (int e = 0; e < 8; ++e) {
                int c = o * 8 + e;
                float f;
                if (c < 500) {
                    f = fbuf[l][c];
                } else if (c < 1500) {
                    f = abuf[l][c - 500];
                } else if (c < 1510) {
                    f = pwv[l][c - 1500];
                } else if (c < 1610) {
                    int r2 = c - 1510, k = r2 / NNB, j = r2 - k * NNB;
                    f = (tkv[l][k] == pav[l][j]) ? 1.f : 0.f;
                } else {
                    f = 0.f;
                }
                __bf16 h = (__bf16)f;
                h8[e] = h;
                l8[e] = (__bf16)(f - (float)h);
            }
            size_t off = ((size_t)rb * 208 + o) * 256 + rlo * 8;
            *(bf16x8*)&Ah[off] = *(bf16x8*)h8;
            *(bf16x8*)&Al[off] = *(bf16x8*)l8;
        }
    }
}

// ---------------- merged weight prep: W1 and W2 -> tiled hi-only (64-col blocks) ----
__global__ __launch_bounds__(256) void k_prep_wt(const float* __restrict__ W1,
                                                 const float* __restrict__ W2,
                                                 __bf16* __restrict__ T1,
                                                 __bf16* __restrict__ T2) {
    int bx = blockIdx.x, n0 = blockIdx.y * 64;
    const float* W; __bf16* T; int K, NKT, kp0;
    if (bx < KP1 / 64) { W = W1; T = T1; K = INDIM; NKT = NKT1; kp0 = bx * 64; }
    else               { W = W2; T = T2; K = HDIM;  NKT = NKT2; kp0 = (bx - KP1 / 64) * 64; }
    __shared__ float lds[64][65];
    int t = threadIdx.x;
    int cc = t & 63, r0 = t >> 6;
    #pragma unroll
    for (int i = 0; i < 16; ++i) {
        int rr = r0 + i * 4;
        int kp = kp0 + rr;
        lds[rr][cc] = (kp < K) ? W[(size_t)kp * HDIM + n0 + cc] : 0.f;
    }
    __syncthreads();
    int nblk = n0 >> 6;
    #pragma unroll
    for (int s = 0; s < 2; ++s) {
        int o = t + s * 256;
        int rn = o & 63, ko = o >> 6;
        int kp = kp0 + ko * 8;
        int kt = kp >> 5, kc = (kp >> 3) & 3;
        __bf16 h8[8];
        #pragma unroll
        for (int e = 0; e < 8; ++e) h8[e] = (__bf16)lds[ko * 8 + e][rn];
        size_t off = ((size_t)(nblk * NKT + kt) * 4 + kc) * 512 + rn * 8;
        *(bf16x8*)&T[off] = *(bf16x8*)h8;
    }
}

// ---------------- 2-pass split-bf16 GEMM, 32x128 tile, no split-K ----------------
// Grid 1600 = 400 mt x 4 nt, XCD-bijective swizzle. LDS stages {Ah, Bh} (20 KB dbuf);
// Al via per-wave register loads (same (lane,e)->k map: MFMA k-permutation cancels).
// SPLIT_OUT: epilogue = +bias, relu, hi/lo split, tiled write via in-LDS transpose.
template<int NKT, bool SPLIT_OUT>
__global__ __launch_bounds__(256, 4) void k_gemm(
    const __bf16* __restrict__ Ahp, const __bf16* __restrict__ Alp,
    const __bf16* __restrict__ Bhp, const float* __restrict__ bias,
    __bf16* __restrict__ Ch, __bf16* __restrict__ Cl, float* __restrict__ Cf) {
    __shared__ __align__(16) char smem[20480];
    __bf16* sAh = (__bf16*)smem;             // 2 bufs x 1024 bf16
    __bf16* sB  = (__bf16*)(smem + 4096);    // 2 bufs x 4096 bf16
    int tid = threadIdx.x, wid = tid >> 6, lane = tid & 63;
    int id = blockIdx.x;
    int swz = (id & 7) * 200 + (id >> 3);    // bijective: 1600 % 8 == 0
    int nt = swz & 3, mt = swz >> 2;         // mt in [0,400)

    auto stage = [&](int kk, int buf) {
        #pragma unroll
        for (int j = 0; j < 3; ++j) {
            int seg = wid + 4 * j;           // 0..11
            if (seg < 2) {
                gload16(Ahp + (size_t)(mt * NKT + kk) * 1024 + seg * 512 + lane * 8,
                        sAh + buf * 1024 + seg * 512);
            } else if (seg < 10) {
                int s = seg - 2, q = s >> 2, kc = s & 3;
                gload16(Bhp + ((size_t)((2 * nt + q) * NKT + kk) * 4 + kc) * 512 + lane * 8,
                        sB + buf * 4096 + (kc * 128 + q * 64) * 8);
            }
        }
    };

    int wr = wid >> 1, wc = wid & 1;         // wave-tile 16 rows x 64 cols
    int lrow = lane & 15, lk = lane >> 4;
    f32x4 acc[4] = {};

    stage(0, 0);
    for (int kk = 0; kk < NKT; ++kk) {
        int buf = kk & 1;
        __syncthreads();
        // A-lo register load first (oldest vmcnt entry -> counted wait, not drain)
        size_t abase = ((size_t)(mt * NKT + kk) * 4 + lk) * 256 + (wr * 16 + lrow) * 8;
        bf16x8 al = *(const bf16x8*)(Alp + abase);
        if (kk + 1 < NKT) stage(kk + 1, buf ^ 1);
        bf16x8 ah = *(const bf16x8*)(sAh + buf * 1024 + (lk * 32 + wr * 16 + lrow) * 8);
        bf16x8 bh[4];
        #pragma unroll
        for (int j = 0; j < 4; ++j)
            bh[j] = *(const bf16x8*)(sB + buf * 4096 + (lk * 128 + wc * 64 + j * 16 + lrow) * 8);
        #pragma unroll
        for (int j = 0; j < 4; ++j) {
            acc[j] = __builtin_amdgcn_mfma_f32_16x16x32_bf16(ah, bh[j], acc[j], 0, 0, 0);
            acc[j] = __builtin_amdgcn_mfma_f32_16x16x32_bf16(al, bh[j], acc[j], 0, 0, 0);
        }
    }

    if (SPLIT_OUT) {
        // epilogue: +b, relu, split, tiled write (32-row blocks) via LDS transpose
        __syncthreads();
        float* sE = (float*)smem;            // 32 x 132 fp32 = 16.9 KB
        #pragma unroll
        for (int j = 0; j < 4; ++j)
            #pragma unroll
            for (int r = 0; r < 4; ++r)
                sE[(wr * 16 + lk * 4 + r) * 132 + wc * 64 + j * 16 + lrow] = acc[j][r];
        __syncthreads();
        int l2 = tid & 31, og2 = tid >> 5;
        #pragma unroll
        for (int s2 = 0; s2 < 2; ++s2) {
            int o = og2 + 8 * s2;            // 0..15 local octet
            int n0 = nt * 128 + o * 8;
            f32x4 v0 = *(f32x4*)&sE[l2 * 132 + o * 8];
            f32x4 v1 = *(f32x4*)&sE[l2 * 132 + o * 8 + 4];
            f32x4 b0 = *(const f32x4*)&bias[n0];
            f32x4 b1v = *(const f32x4*)&bias[n0 + 4];
            __bf16 h8[8], l8[8];
            #pragma unroll
            for (int i = 0; i < 4; ++i) {
                float c = fmaxf(v0[i] + b0[i], 0.f);
                __bf16 h = (__bf16)c;
                h8[i] = h; l8[i] = (__bf16)(c - (float)h);
                c = fmaxf(v1[i] + b1v[i], 0.f);
                h = (__bf16)c;
                h8[4 + i] = h; l8[4 + i] = (__bf16)(c - (float)h);
            }
            size_t off = ((size_t)mt * 64 + nt * 16 + o) * 256 + l2 * 8;
            *(bf16x8*)&Ch[off] = *(bf16x8*)h8;
            *(bf16x8*)&Cl[off] = *(bf16x8*)l8;
        }
    } else {
        #pragma unroll
        for (int j = 0; j < 4; ++j) {
            int n = nt * 128 + wc * 64 + j * 16 + lrow;
            float bv = bias[n];
            #pragma unroll
            for (int r = 0; r < 4; ++r) {
                int mrow = mt * 32 + wr * 16 + lk * 4 + r;
                Cf[(size_t)mrow * HDIM + n] = fmaxf(acc[j][r] + bv, 0.f);
            }
        }
    }
}

// ---------------- output: h2act @ W3 + b3 ; wave per row ----------------
__global__ __launch_bounds__(256) void k_out(const float* __restrict__ h2,
                                             const float* __restrict__ W3,
                                             const float* __restrict__ b3,
                                             float* __restrict__ out) {
    int wid = threadIdx.x >> 6, lane = threadIdx.x & 63;
    int row = blockIdx.x * 4 + wid;
    const float* hp = h2 + (size_t)row * HDIM + lane * 8;
    f32x4 a0 = *(const f32x4*)hp;
    f32x4 a1 = *(const f32x4*)(hp + 4);
    float h[8];
    #pragma unroll
    for (int i = 0; i < 4; ++i) { h[i] = a0[i]; h[4 + i] = a1[i]; }
    float acc[NOUT];
    #pragma unroll
    for (int n = 0; n < NOUT; ++n) acc[n] = 0.f;
    int k0 = lane * 8;
    #pragma unroll
    for (int i = 0; i < 8; ++i) {
        float hv = h[i];
        const float* w = W3 + (size_t)(k0 + i) * NOUT;
        #pragma unroll
        for (int n = 0; n < NOUT; ++n) acc[n] += hv * w[n];
    }
    #pragma unroll
    for (int off = 32; off >= 1; off >>= 1)
        #pragma unroll
        for (int n = 0; n < NOUT; ++n) acc[n] += __shfl_down(acc[n], off, 64);
    if (lane == 0) {
        #pragma unroll
        for (int n = 0; n < NOUT; ++n) out[(size_t)row * NOUT + n] = acc[n] + b3[n];
    }
}

extern "C" void kernel_launch(void* const* d_in, const int* in_sizes, int n_in,
                              void* d_out, int out_size, void* d_ws, size_t ws_size,
                              hipStream_t stream) {
    const float* beta    = (const float*)d_in[0];
    const float* actions = (const float*)d_in[1];
    const float* power   = (const float*)d_in[2];
    const int*   prev    = (const int*)d_in[3];
    const float* W1      = (const float*)d_in[4];
    const float* b1      = (const float*)d_in[5];
    const float* W2      = (const float*)d_in[6];
    const float* b2      = (const float*)d_in[7];
    const float* W3      = (const float*)d_in[8];
    const float* b3      = (const float*)d_in[9];
    float* out = (float*)d_out;

    char* ws = (char*)d_ws;
    size_t off = 0;
    auto alloc = [&](size_t bytes) { void* p = ws + off; off += (bytes + 255) & ~(size_t)255; return p; };
    float*  total_beta = (float*) alloc((size_t)NROWS * MTASK * 4);
    int*    tasks      = (int*)   alloc((size_t)NROWS * MTOP * 4);
    int*    neighbors  = (int*)   alloc((size_t)NROWS * NNB * 4);
    __bf16* Ah   = (__bf16*)alloc((size_t)NROWS * KP1 * 2);
    __bf16* Al   = (__bf16*)alloc((size_t)NROWS * KP1 * 2);
    __bf16* W1th = (__bf16*)alloc((size_t)HDIM * KP1 * 2);
    __bf16* W2th = (__bf16*)alloc((size_t)HDIM * HDIM * 2);
    __bf16* h1h  = (__bf16*)alloc((size_t)NROWS * HDIM * 2);
    __bf16* h1l  = (__bf16*)alloc((size_t)NROWS * HDIM * 2);
    float*  P    = (float*) alloc(PLANE * 4);   // h2act

    k_topk<<<NROWS / 4, 256, 0, stream>>>(beta, total_beta, tasks);
    k_nbrs<<<NROWS / 4, 256, 0, stream>>>(total_beta, tasks, neighbors);
    k_build_inputs<<<NROWS / 8, 256, 0, stream>>>(beta, actions, power, prev, tasks,
                                                  neighbors, Ah, Al);
    {
        dim3 gp(KP1 / 64 + HDIM / 64, HDIM / 64);
        k_prep_wt<<<gp, 256, 0, stream>>>(W1, W2, W1th, W2th);
    }
    // GEMM1: 32x128 tile, grid 1600, fused b1+relu+split epilogue -> h1h/h1l (tiled)
    k_gemm<NKT1, true><<<1600, 256, 0, stream>>>(Ah, Al, W1th, b1, h1h, h1l, nullptr);
    // GEMM2: 32x128 tile, grid 1600, b2+relu -> h2act fp32
    k_gemm<NKT2, false><<<1600, 256, 0, stream>>>(h1h, h1l, W2th, b2, nullptr, nullptr, P);
    k_out<<<NROWS / 4, 256, 0, stream>>>(P, W3, b3, out);
}